// Round 9
// baseline (722.163 us; speedup 1.0000x reference)
//
#include <hip/hip_runtime.h>
#include <cstdint>
#include <cstddef>

// N=100000, E=20000, P=1600000, din=128, dh=64, H=4, DCAT=512, C=40
static constexpr int DIN = 128;
static constexpr int DH = 64;
static constexpr int NH = 4;
static constexpr int DCAT = 512;
static constexpr int NC = 40;
static constexpr int E_CONST = 20000;
// 2-level bucket sort with locality sub-keys:
// v-sort key = (v>>9)*10 + (e>>11)   -> 196 v-buckets x 10 e-chunks (2 MB Ycat slices)
// e-sort key = (e>>7)*25 + (v>>12)   -> 157 e-buckets x 25 v-chunks (2 MB Xbi slices)
static constexpr int SH_V = 9, SUBD_V = 512;
static constexpr int SH_E = 7, SUBD_E = 128;
static constexpr int ECH = 11, NSUB_E = 10;   // e-chunk shift / count (within v-sort key)
static constexpr int VCH = 12, NSUB_V = 25;   // v-chunk shift / count (within e-sort key)
static constexpr int NKV = 196 * NSUB_E;      // 1960 fine v-keys
static constexpr int NKE = 157 * NSUB_V;      // 3925 fine e-keys
static constexpr int CHUNKA = 4096;           // pairs per scatter block

typedef unsigned short u16;
typedef __attribute__((ext_vector_type(4))) unsigned short u16x4;
typedef __attribute__((ext_vector_type(8))) unsigned short u16x8;
typedef __attribute__((ext_vector_type(8))) short bf16x8;
typedef __attribute__((ext_vector_type(4))) float f32x4;

static __device__ __forceinline__ float bf2f(u16 u) {
    union { unsigned int i; float f; } x;
    x.i = ((unsigned int)u) << 16;
    return x.f;
}
static __device__ __forceinline__ u16 f2bf(float f) {
    union { float f; unsigned int i; } x;
    x.f = f;
    unsigned int r = x.i + 0x7fffu + ((x.i >> 16) & 1u);
    return (u16)(r >> 16);
}
static __device__ __forceinline__ int keyV(int v, int e) { return (v >> SH_V) * NSUB_E + (e >> ECH); }
static __device__ __forceinline__ int keyE(int e, int v) { return (e >> SH_E) * NSUB_V + (v >> VCH); }

// ---------------- CSR build via 2-level bucket sort with locality sub-keys ----------------

__global__ void k_hist2(const int* __restrict__ pv, const int* __restrict__ pe,
                        int* __restrict__ btot_v, int* __restrict__ btot_e, int P) {
    __shared__ int cv[NKV], ce[NKE];
    int tid = threadIdx.x;
    for (int k = tid; k < NKV; k += 256) cv[k] = 0;
    for (int k = tid; k < NKE; k += 256) ce[k] = 0;
    __syncthreads();
    int p0 = blockIdx.x * CHUNKA;
    #pragma unroll
    for (int j = 0; j < CHUNKA / 256; ++j) {
        int p = p0 + tid + j * 256;
        if (p < P) {
            int v = pv[p], e = pe[p];
            atomicAdd(&cv[keyV(v, e)], 1);
            atomicAdd(&ce[keyE(e, v)], 1);
        }
    }
    __syncthreads();
    for (int k = tid; k < NKV; k += 256)
        if (cv[k]) atomicAdd(&btot_v[k], cv[k]);
    for (int k = tid; k < NKE; k += 256)
        if (ce[k]) atomicAdd(&btot_e[k], ce[k]);
}

// in-place exclusive scan, a[n]=total (single block)
__global__ void k_scan_small(int* __restrict__ a, int n) {
    __shared__ int wsum[16];
    __shared__ int carry_s;
    int tid = threadIdx.x;
    int lane = tid & 63;
    int w = tid >> 6;
    if (tid == 0) carry_s = 0;
    __syncthreads();
    for (int base = 0; base < n; base += 1024) {
        int i = base + tid;
        int v = (i < n) ? a[i] : 0;
        int x = v;
        #pragma unroll
        for (int off = 1; off < 64; off <<= 1) {
            int t = __shfl_up(x, off);
            if (lane >= off) x += t;
        }
        if (lane == 63) wsum[w] = x;
        __syncthreads();
        int woff = 0;
        for (int k = 0; k < w; ++k) woff += wsum[k];
        int carry = carry_s;
        if (i < n) a[i] = carry + woff + x - v;
        int tot = 0;
        for (int k = 0; k < 16; ++k) tot += wsum[k];
        __syncthreads();
        if (tid == 0) carry_s = carry + tot;
        __syncthreads();
    }
    if (tid == 0) a[n] = carry_s;
}

// scatter pairs into fine-bucket-grouped arrays (per-(block,bucket) contiguous windows)
__global__ void k_scatter2way(const int* __restrict__ pv, const int* __restrict__ pe,
                              const int* __restrict__ bstart_v, const int* __restrict__ bstart_e,
                              int* __restrict__ cur_v, int* __restrict__ cur_e,
                              uint2* __restrict__ sorted_v, uint2* __restrict__ sorted_e, int P) {
    __shared__ int cv[NKV], posv[NKV], ce[NKE], pose[NKE];
    int tid = threadIdx.x;
    for (int k = tid; k < NKV; k += 256) cv[k] = 0;
    for (int k = tid; k < NKE; k += 256) ce[k] = 0;
    __syncthreads();
    int p0 = blockIdx.x * CHUNKA;
    int kv[CHUNKA / 256], ke[CHUNKA / 256];
    #pragma unroll
    for (int j = 0; j < CHUNKA / 256; ++j) {
        int p = p0 + tid + j * 256;
        if (p < P) {
            kv[j] = pv[p];
            ke[j] = pe[p];
            atomicAdd(&cv[keyV(kv[j], ke[j])], 1);
            atomicAdd(&ce[keyE(ke[j], kv[j])], 1);
        } else {
            kv[j] = -1;
            ke[j] = -1;
        }
    }
    __syncthreads();
    for (int k = tid; k < NKV; k += 256)
        if (cv[k]) posv[k] = bstart_v[k] + atomicAdd(&cur_v[k], cv[k]);
    for (int k = tid; k < NKE; k += 256)
        if (ce[k]) pose[k] = bstart_e[k] + atomicAdd(&cur_e[k], ce[k]);
    __syncthreads();
    #pragma unroll
    for (int j = 0; j < CHUNKA / 256; ++j) {
        if (kv[j] >= 0) {
            int iv = atomicAdd(&posv[keyV(kv[j], ke[j])], 1);
            sorted_v[iv] = make_uint2((unsigned)kv[j], (unsigned)ke[j]);
            int ie = atomicAdd(&pose[keyE(ke[j], kv[j])], 1);
            sorted_e[ie] = make_uint2((unsigned)ke[j], (unsigned)kv[j]);
        }
    }
}

// per-bucket CSR build, one block per coarse bucket; contiguous spans preserve sub-key order
template <int SUBD, int SH, int NSUB>
__global__ void k_build(const uint2* __restrict__ sorted, const int* __restrict__ bstart,
                        int* __restrict__ start_out, int* __restrict__ deg_out,
                        int* __restrict__ csr_out, int D) {
    __shared__ int deg[SUBD], pos[SUBD];
    int b = blockIdx.x;
    int tid = threadIdx.x;
    int base_key = b << SH;
    int s0 = bstart[b * NSUB];
    int cnt = bstart[(b + 1) * NSUB] - s0;
    for (int k = tid; k < SUBD; k += 256) deg[k] = 0;
    __syncthreads();
    int span = (cnt + 255) / 256;
    int i0 = tid * span;
    int i1 = i0 + span < cnt ? i0 + span : cnt;
    for (int i = i0; i < i1; ++i)
        atomicAdd(&deg[(int)sorted[s0 + i].x - base_key], 1);
    __syncthreads();
    if (tid < 64) {
        int carry = 0;
        for (int base = 0; base < SUBD; base += 64) {
            int d = deg[base + tid];
            int x = d;
            #pragma unroll
            for (int off = 1; off < 64; off <<= 1) {
                int t = __shfl_up(x, off);
                if (tid >= off) x += t;
            }
            pos[base + tid] = carry + x - d;
            carry += __shfl(x, 63);
        }
    }
    __syncthreads();
    for (int k = tid; k < SUBD; k += 256) {
        int key = base_key + k;
        if (key < D) {
            start_out[key] = s0 + pos[k];
            deg_out[key] = deg[k];
        }
    }
    __syncthreads();
    for (int i = i0; i < i1; ++i) {
        uint2 pr = sorted[s0 + i];
        int loc = (int)pr.x - base_key;
        int idx = atomicAdd(&pos[loc], 1);
        csr_out[s0 + idx] = (int)pr.y;
    }
}

// ---------------- weight prep ----------------

__global__ void k_wav(const float* __restrict__ W1, const float* __restrict__ b1,
                      const float* __restrict__ av1, float* __restrict__ wav,
                      float* __restrict__ bav) {
    int h = blockIdx.x;
    int k = threadIdx.x;
    float s = 0.f;
    for (int j = 0; j < DH; ++j) s += W1[(size_t)(h * DIN + k) * DH + j] * av1[h * DH + j];
    wav[h * DIN + k] = s;
    if (k == 0) {
        float t = 0.f;
        for (int j = 0; j < DH; ++j) t += b1[h * DH + j] * av1[h * DH + j];
        bav[h] = t;
    }
}

__global__ void k_build_wcatT(const float* __restrict__ W1, u16* __restrict__ WcatT) {
    int idx = blockIdx.x * 256 + threadIdx.x;
    if (idx >= 256 * DIN) return;
    int c = idx >> 7, k = idx & 127;
    int h = c >> 6, j = c & 63;
    WcatT[c * DIN + k] = f2bf(W1[((size_t)h * DIN + k) * DH + j]);
}

__global__ void k_build_w2T(const float* __restrict__ W2, u16* __restrict__ W2T) {
    int idx = blockIdx.x * 256 + threadIdx.x;
    if (idx >= 48 * DCAT) return;
    int c = idx >> 9, k = idx & 511;
    float v = (c < NC) ? W2[(size_t)k * NC + c] : 0.f;
    W2T[c * DCAT + k] = f2bf(v);
}

// ---------------- conversion + node attention term (layer 1), both inputs ----------------
__global__ void k_conv(const float* __restrict__ X0, const float* __restrict__ X1,
                       const float* __restrict__ wav, const float* __restrict__ bav,
                       u16* __restrict__ Xbi, float* __restrict__ sv8, int N) {
    int wave = (blockIdx.x * blockDim.x + threadIdx.x) >> 6;
    int lane = threadIdx.x & 63;
    if (wave >= N) return;
    int xz = blockIdx.y;
    const float* X = xz ? X1 : X0;
    float2 a = *(const float2*)(X + (size_t)wave * DIN + lane * 2);
    unsigned int packed = (unsigned int)f2bf(a.x) | ((unsigned int)f2bf(a.y) << 16);
    *(unsigned int*)(Xbi + (size_t)wave * 256 + xz * 128 + lane * 2) = packed;
    float s[NH];
    #pragma unroll
    for (int h = 0; h < NH; ++h) {
        float2 wv = *(const float2*)(wav + h * DIN + lane * 2);
        float t = a.x * wv.x + a.y * wv.y;
        #pragma unroll
        for (int off = 32; off >= 1; off >>= 1) t += __shfl_xor(t, off);
        s[h] = t;
    }
    if (lane == 0) {
        #pragma unroll
        for (int h = 0; h < NH; ++h) sv8[(size_t)wave * 8 + h * 2 + xz] = s[h] + bav[h];
    }
}

// ---------------- edge mean (bf16, D=128), both inputs, unroll-3 pipelined ----------------
__global__ void k_edge_mean1(const u16* __restrict__ Xbi, const int* __restrict__ start_e,
                             const int* __restrict__ deg_e, const int* __restrict__ csr_e_v,
                             u16* __restrict__ Xbar0, u16* __restrict__ Xbar1, int E) {
    int wave = (blockIdx.x * blockDim.x + threadIdx.x) >> 6;
    int lane = threadIdx.x & 63;
    if (wave >= E) return;
    int s = start_e[wave], t = s + deg_e[wave];
    int q = lane >> 4, c = lane & 15;
    float a0[8], a1[8];
    #pragma unroll
    for (int j = 0; j < 8; ++j) { a0[j] = 0.f; a1[j] = 0.f; }
    int i = s + q;
    u16x8 y0A = {0}, y1A = {0}, y0B = {0}, y1B = {0}, y0C = {0}, y1C = {0};
#define EM1_LOAD(Y0, Y1, IDX) { int v_ = csr_e_v[IDX]; \
        const u16* yp_ = Xbi + (size_t)v_ * 256 + c * 8; \
        Y0 = *(const u16x8*)yp_; Y1 = *(const u16x8*)(yp_ + 128); }
#define EM1_CONSUME(Y0, Y1) { \
        _Pragma("unroll") \
        for (int j = 0; j < 8; ++j) { a0[j] += bf2f(Y0[j]); a1[j] += bf2f(Y1[j]); } }
    if (i < t) EM1_LOAD(y0A, y1A, i);
    if (i + 4 < t) EM1_LOAD(y0B, y1B, i + 4);
    if (i + 8 < t) EM1_LOAD(y0C, y1C, i + 8);
    for (; i + 8 < t; i += 12) {
        EM1_CONSUME(y0A, y1A);
        if (i + 12 < t) EM1_LOAD(y0A, y1A, i + 12);
        EM1_CONSUME(y0B, y1B);
        if (i + 16 < t) EM1_LOAD(y0B, y1B, i + 16);
        EM1_CONSUME(y0C, y1C);
        if (i + 20 < t) EM1_LOAD(y0C, y1C, i + 20);
    }
    if (i < t) EM1_CONSUME(y0A, y1A);
    if (i + 4 < t) EM1_CONSUME(y0B, y1B);
#undef EM1_LOAD
#undef EM1_CONSUME
    #pragma unroll
    for (int j = 0; j < 8; ++j) {
        a0[j] += __shfl_xor(a0[j], 16);
        a0[j] += __shfl_xor(a0[j], 32);
        a1[j] += __shfl_xor(a1[j], 16);
        a1[j] += __shfl_xor(a1[j], 32);
    }
    int deg = t - s;
    float inv = 1.f / (float)(deg > 1 ? deg : 1);
    if (q == 0) {
        u16x8 r0, r1;
        #pragma unroll
        for (int j = 0; j < 8; ++j) { r0[j] = f2bf(a0[j] * inv); r1[j] = f2bf(a1[j] * inv); }
        *(u16x8*)(Xbar0 + (size_t)wave * DIN + c * 8) = r0;
        *(u16x8*)(Xbar1 + (size_t)wave * DIN + c * 8) = r1;
    }
}

// ---------------- MFMA GEMM with fused row-dot epilogue ----------------
template <int KDIM, int NTILES, int DOTMODE>
__global__ __launch_bounds__(256) void k_gemm_mfma(const u16* __restrict__ A0,
                                                   const u16* __restrict__ A1, int M,
                                                   const u16* __restrict__ Bt,
                                                   const float* __restrict__ bias,
                                                   u16* __restrict__ out0, u16* __restrict__ out1,
                                                   int ldo, int ncols,
                                                   const float* __restrict__ dvec,
                                                   float* __restrict__ dout) {
    constexpr int LDB = KDIM + 8;
    __shared__ u16 Bs[NTILES * 16 * LDB];
    const u16* A = blockIdx.z ? A1 : A0;
    u16* out = blockIdx.z ? out1 : out0;
    int tid = threadIdx.x;
    int colbase = blockIdx.y * NTILES * 16;
    const u16* Btblk = Bt + (size_t)colbase * KDIM;
    for (int idx = tid * 4; idx < NTILES * 16 * KDIM; idx += 256 * 4) {
        int c = idx / KDIM, k = idx % KDIM;
        *(u16x4*)&Bs[c * LDB + k] = *(const u16x4*)(Btblk + c * KDIM + k);
    }
    __syncthreads();
    int w = tid >> 6, lane = tid & 63;
    int r0 = blockIdx.x * 64 + w * 16;
    int arow = r0 + (lane & 15);
    bool avalid = arow < M;
    const u16* ap = A + (size_t)arow * KDIM + (lane >> 4) * 8;
    f32x4 acc[NTILES];
    #pragma unroll
    for (int nt = 0; nt < NTILES; ++nt) acc[nt] = (f32x4){0.f, 0.f, 0.f, 0.f};
    #pragma unroll
    for (int k0 = 0; k0 < KDIM; k0 += 32) {
        bf16x8 a = (bf16x8)(short)0;
        if (avalid) a = *(const bf16x8*)(ap + k0);
        #pragma unroll
        for (int nt = 0; nt < NTILES; ++nt) {
            bf16x8 b = *(const bf16x8*)&Bs[(nt * 16 + (lane & 15)) * LDB + k0 + (lane >> 4) * 8];
            acc[nt] = __builtin_amdgcn_mfma_f32_16x16x32_bf16(a, b, acc[nt], 0, 0, 0);
        }
    }
    #pragma unroll
    for (int j = 0; j < 4; ++j) {
        int row = r0 + (lane >> 4) * 4 + j;
        float pA = 0.f, pB = 0.f;
        #pragma unroll
        for (int nt = 0; nt < NTILES; ++nt) {
            int col = colbase + nt * 16 + (lane & 15);
            bool cok = col < ncols;
            float val = cok ? acc[nt][j] + bias[col] : 0.f;
            if (DOTMODE == 1) {
                float dv = dvec[col];
                if (nt < NTILES / 2) pA += val * dv; else pB += val * dv;
            } else if (DOTMODE == 2) {
                pA += cok ? val * dvec[col] : 0.f;
            }
            if (row < M && cok) out[(size_t)row * ldo + col] = f2bf(val);
        }
        if (DOTMODE) {
            pA += __shfl_xor(pA, 1);
            pA += __shfl_xor(pA, 2);
            pA += __shfl_xor(pA, 4);
            pA += __shfl_xor(pA, 8);
            if (DOTMODE == 1) {
                pB += __shfl_xor(pB, 1);
                pB += __shfl_xor(pB, 2);
                pB += __shfl_xor(pB, 4);
                pB += __shfl_xor(pB, 8);
            }
            if ((lane & 15) == 0 && row < M) {
                if (DOTMODE == 1) {
                    int hbase = blockIdx.y * 2;
                    int z = blockIdx.z;
                    dout[(size_t)row * 8 + hbase * 2 + z] = pA;
                    dout[(size_t)row * 8 + (hbase + 1) * 2 + z] = pB;
                } else {
                    dout[row] = pA;
                }
            }
        }
    }
}

// ---------------- fused node pass (layer 1), both inputs, simple loop ----------------
// Lists are now ~e-ascending (2 MB Ycat chunks) -> concurrent waves share an L2-resident window.
__global__ void k_node_pass1(const u16* __restrict__ Ycat, const float* __restrict__ se8,
                             const float* __restrict__ sv8, const int* __restrict__ start_v,
                             const int* __restrict__ deg_v, const int* __restrict__ csr_v_e,
                             u16* __restrict__ hbuf, int N) {
    int wave = (blockIdx.x * blockDim.x + threadIdx.x) >> 6;
    int lane = threadIdx.x & 63;
    if (wave >= N) return;
    int p0 = start_v[wave], p1 = p0 + deg_v[wave];
    int g = lane >> 5;
    int c = lane & 31;
    int h = c >> 3;
    u16* orow = hbuf + (size_t)wave * DCAT + c * 8;
    if (p1 == p0) {
        if (g == 0) {
            u16x8 z8 = {0, 0, 0, 0, 0, 0, 0, 0};
            *(u16x8*)orow = z8;
            *(u16x8*)(orow + 256) = z8;
        }
        return;
    }
    float sv0 = sv8[(size_t)wave * 8 + h * 2];
    float sv1 = sv8[(size_t)wave * 8 + h * 2 + 1];
    float den0 = 0.f, den1 = 0.f;
    float a0[8], a1[8];
    #pragma unroll
    for (int j = 0; j < 8; ++j) { a0[j] = 0.f; a1[j] = 0.f; }
    for (int i = p0 + g; i < p1; i += 2) {
        int e = csr_v_e[i];
        float2 s2 = *(const float2*)(se8 + e * 8 + h * 2);
        float x0 = s2.x + sv0;
        float x1 = s2.y + sv1;
        x0 = fmaxf(x0, 0.2f * x0);
        x1 = fmaxf(x1, 0.2f * x1);
        float e0 = __expf(x0);
        float e1 = __expf(x1);
        den0 += e0;
        den1 += e1;
        const u16* yp = Ycat + (size_t)e * 512 + c * 8;
        u16x8 q0 = *(const u16x8*)yp;
        u16x8 q1 = *(const u16x8*)(yp + 256);
        #pragma unroll
        for (int j = 0; j < 8; ++j) { a0[j] += e0 * bf2f(q0[j]); a1[j] += e1 * bf2f(q1[j]); }
    }
    den0 += __shfl_xor(den0, 32);
    den1 += __shfl_xor(den1, 32);
    #pragma unroll
    for (int j = 0; j < 8; ++j) {
        a0[j] += __shfl_xor(a0[j], 32);
        a1[j] += __shfl_xor(a1[j], 32);
    }
    float i0 = 1.f / den0, i1 = 1.f / den1;
    u16x8 r0, r1;
    #pragma unroll
    for (int j = 0; j < 8; ++j) {
        float o0 = a0[j] * i0;
        float o1 = a1[j] * i1;
        o0 = o0 > 0.f ? o0 : __expf(o0) - 1.f;
        o1 = o1 > 0.f ? o1 : __expf(o1) - 1.f;
        r0[j] = f2bf(o0);
        r1[j] = f2bf(o1);
    }
    if (g == 0) {
        *(u16x8*)orow = r0;
        *(u16x8*)(orow + 256) = r1;
    }
}

// ---------------- layer 2 small kernels ----------------

__global__ void k_edge_mean2(const u16* __restrict__ Xp2b, const int* __restrict__ start_e,
                             const int* __restrict__ deg_ea, const int* __restrict__ csr_e_v,
                             u16* __restrict__ Y2b, const float* __restrict__ ae2,
                             float* __restrict__ se2, int E) {
    int wave = (blockIdx.x * blockDim.x + threadIdx.x) >> 6;
    int lane = threadIdx.x & 63;
    if (wave >= E) return;
    int s = start_e[wave], t = s + deg_ea[wave];
    int g = lane >> 4, c = lane & 15;
    bool act = c < 10;
    float acc[4];
    #pragma unroll
    for (int j = 0; j < 4; ++j) acc[j] = 0.f;
    for (int i = s + g; i < t; i += 4) {
        int v = csr_e_v[i];
        if (act) {
            u16x4 y = *(const u16x4*)(Xp2b + (size_t)v * NC + c * 4);
            acc[0] += bf2f(y.x);
            acc[1] += bf2f(y.y);
            acc[2] += bf2f(y.z);
            acc[3] += bf2f(y.w);
        }
    }
    #pragma unroll
    for (int j = 0; j < 4; ++j) {
        acc[j] += __shfl_xor(acc[j], 16);
        acc[j] += __shfl_xor(acc[j], 32);
    }
    int deg = t - s;
    float inv = 1.f / (float)(deg > 1 ? deg : 1);
    float p = 0.f;
    if (act) {
        float4 ae = *(const float4*)(ae2 + c * 4);
        float y0 = acc[0] * inv, y1 = acc[1] * inv, y2 = acc[2] * inv, y3 = acc[3] * inv;
        p = y0 * ae.x + y1 * ae.y + y2 * ae.z + y3 * ae.w;
        if (g == 0) {
            u16x4 r = {f2bf(y0), f2bf(y1), f2bf(y2), f2bf(y3)};
            *(u16x4*)(Y2b + (size_t)wave * NC + c * 4) = r;
        }
    }
    #pragma unroll
    for (int off = 8; off >= 1; off >>= 1) p += __shfl_xor(p, off);
    if (lane == 0) se2[wave] = p;
}

__global__ void k_node_pass2(const u16* __restrict__ Y2b, const float* __restrict__ se2,
                             const float* __restrict__ sv2, const int* __restrict__ start_v,
                             const int* __restrict__ deg_va, const int* __restrict__ csr_v_e,
                             float* __restrict__ out, int N) {
    int wave = (blockIdx.x * blockDim.x + threadIdx.x) >> 6;
    int lane = threadIdx.x & 63;
    if (wave >= N) return;
    int s = start_v[wave], t = s + deg_va[wave];
    int g = lane >> 4, c = lane & 15;
    bool act = c < 10;
    float* orow = out + (size_t)wave * NC;
    if (t == s) {
        if (g == 0 && act) *(float4*)(orow + c * 4) = make_float4(0.f, 0.f, 0.f, 0.f);
        return;
    }
    float svv = sv2[wave];
    float den = 0.f;
    float acc[4];
    #pragma unroll
    for (int j = 0; j < 4; ++j) acc[j] = 0.f;
    for (int i = s + g; i < t; i += 4) {
        int e = csr_v_e[i];
        float x = se2[e] + svv;
        x = fmaxf(x, 0.2f * x);
        float ex = __expf(x);
        den += ex;
        if (act) {
            u16x4 y = *(const u16x4*)(Y2b + (size_t)e * NC + c * 4);
            acc[0] += ex * bf2f(y.x);
            acc[1] += ex * bf2f(y.y);
            acc[2] += ex * bf2f(y.z);
            acc[3] += ex * bf2f(y.w);
        }
    }
    den += __shfl_xor(den, 16);
    den += __shfl_xor(den, 32);
    #pragma unroll
    for (int j = 0; j < 4; ++j) {
        acc[j] += __shfl_xor(acc[j], 16);
        acc[j] += __shfl_xor(acc[j], 32);
    }
    if (g == 0 && act) {
        float inv = 1.f / den;
        float4 o;
        float* op = &o.x;
        #pragma unroll
        for (int j = 0; j < 4; ++j) {
            float v = acc[j] * inv;
            op[j] = v > 0.f ? v : __expf(v) - 1.f;
        }
        *(float4*)(orow + c * 4) = o;
    }
}

// ---------------- launcher ----------------
extern "C" void kernel_launch(void* const* d_in, const int* in_sizes, int n_in,
                              void* d_out, int out_size, void* d_ws, size_t ws_size,
                              hipStream_t stream) {
    const float* x0 = (const float*)d_in[0];
    const float* x1 = (const float*)d_in[1];
    const float* W1 = (const float*)d_in[2];
    const float* b1 = (const float*)d_in[3];
    const float* ae1 = (const float*)d_in[4];
    const float* av1 = (const float*)d_in[5];
    const float* W2 = (const float*)d_in[6];
    const float* b2 = (const float*)d_in[7];
    const float* ae2 = (const float*)d_in[8];
    const float* av2 = (const float*)d_in[9];
    const int* pe = (const int*)d_in[10];
    const int* pv = (const int*)d_in[11];

    const int N = in_sizes[0] / DIN;  // 100000
    const int P = in_sizes[10];       // 1600000
    const int E = E_CONST;            // 20000
    const int NBKT_V = (N + SUBD_V - 1) / SUBD_V;   // 196
    const int NBKT_E = (E + SUBD_E - 1) / SUBD_E;   // 157

    char* base = (char*)d_ws;
    auto alloc = [&](size_t bytes) -> void* {
        void* p = (void*)base;
        base += (bytes + 255) & ~(size_t)255;
        return p;
    };
    u16* Xbi = (u16*)alloc((size_t)N * 256 * 2);
    u16* hbuf = (u16*)alloc((size_t)N * DCAT * 2);
    u16* Xbar0 = (u16*)alloc((size_t)E * DIN * 2);
    u16* Xbar1 = (u16*)alloc((size_t)E * DIN * 2);
    u16* Ycat = (u16*)alloc((size_t)E * 512 * 2);
    u16* Xp2b = (u16*)alloc((size_t)N * NC * 2);
    u16* Y2b = (u16*)alloc((size_t)E * NC * 2);
    float* se8 = (float*)alloc((size_t)E * 8 * 4);
    float* se2 = (float*)alloc((size_t)E * 4);
    float* sv8 = (float*)alloc((size_t)N * 8 * 4);
    float* sv2 = (float*)alloc((size_t)N * 4);
    float* wav = (float*)alloc((size_t)NH * DIN * 4);
    float* bav = (float*)alloc((size_t)NH * 4);
    u16* WcatT = (u16*)alloc((size_t)256 * DIN * 2);
    u16* W2T = (u16*)alloc((size_t)48 * DCAT * 2);
    uint2* sorted_v = (uint2*)alloc((size_t)P * 8);
    uint2* sorted_e = (uint2*)alloc((size_t)P * 8);
    int* start_v = (int*)alloc((size_t)N * 4);
    int* deg_v = (int*)alloc((size_t)N * 4);
    int* start_e = (int*)alloc((size_t)E * 4);
    int* deg_e = (int*)alloc((size_t)E * 4);
    int* csr_v_e = (int*)alloc((size_t)P * 4);
    int* csr_e_v = (int*)alloc((size_t)P * 4);
    char* zstart = base;
    int* bstart_v = (int*)alloc((size_t)(NKV + 1) * 4);
    int* bstart_e = (int*)alloc((size_t)(NKE + 1) * 4);
    int* cur_v = (int*)alloc((size_t)NKV * 4);
    int* cur_e = (int*)alloc((size_t)NKE * 4);
    size_t zbytes = (size_t)(base - zstart);

    if ((size_t)(base - (char*)d_ws) > ws_size) return;

    hipMemsetAsync(zstart, 0, zbytes, stream);

    dim3 b256(256);
    int nA = (P + CHUNKA - 1) / CHUNKA;   // 391
    k_hist2<<<nA, b256, 0, stream>>>(pv, pe, bstart_v, bstart_e, P);
    k_scan_small<<<1, 1024, 0, stream>>>(bstart_v, NKV);
    k_scan_small<<<1, 1024, 0, stream>>>(bstart_e, NKE);
    k_scatter2way<<<nA, b256, 0, stream>>>(pv, pe, bstart_v, bstart_e, cur_v, cur_e,
                                           sorted_v, sorted_e, P);
    k_build<SUBD_V, SH_V, NSUB_E><<<NBKT_V, b256, 0, stream>>>(sorted_v, bstart_v, start_v,
                                                               deg_v, csr_v_e, N);
    k_build<SUBD_E, SH_E, NSUB_V><<<NBKT_E, b256, 0, stream>>>(sorted_e, bstart_e, start_e,
                                                               deg_e, csr_e_v, E);

    k_wav<<<NH, DIN, 0, stream>>>(W1, b1, av1, wav, bav);
    k_build_wcatT<<<(256 * DIN + 255) / 256, b256, 0, stream>>>(W1, WcatT);
    k_build_w2T<<<(48 * DCAT + 255) / 256, b256, 0, stream>>>(W2, W2T);

    int gN4 = (N + 3) / 4;
    int gE4 = (E + 3) / 4;
    dim3 gconv(gN4, 2);
    k_conv<<<gconv, b256, 0, stream>>>(x0, x1, wav, bav, Xbi, sv8, N);

    k_edge_mean1<<<gE4, b256, 0, stream>>>(Xbi, start_e, deg_e, csr_e_v, Xbar0, Xbar1, E);
    dim3 g1((E + 63) / 64, 2, 2);
    k_gemm_mfma<DIN, 8, 1><<<g1, b256, 0, stream>>>(Xbar0, Xbar1, E, WcatT, b1,
                                                    Ycat, Ycat + 256, 512, 256, ae1, se8);
    k_node_pass1<<<gN4, b256, 0, stream>>>(Ycat, se8, sv8, start_v, deg_v, csr_v_e, hbuf, N);

    dim3 g2((N + 63) / 64, 1, 1);
    k_gemm_mfma<DCAT, 3, 2><<<g2, b256, 0, stream>>>(hbuf, hbuf, N, W2T, b2, Xp2b, Xp2b,
                                                     NC, NC, av2, sv2);
    k_edge_mean2<<<gE4, b256, 0, stream>>>(Xp2b, start_e, deg_e, csr_e_v, Y2b, ae2, se2, E);
    k_node_pass2<<<gN4, b256, 0, stream>>>(Y2b, se2, sv2, start_v, deg_v, csr_v_e,
                                           (float*)d_out, N);
}

// Round 10
// 666.328 us; speedup vs baseline: 1.0838x; 1.0838x over previous
//
#include <hip/hip_runtime.h>
#include <cstdint>
#include <cstddef>

// N=100000, E=20000, P=1600000, din=128, dh=64, H=4, DCAT=512, C=40
static constexpr int DIN = 128;
static constexpr int DH = 64;
static constexpr int NH = 4;
static constexpr int DCAT = 512;
static constexpr int NC = 40;
static constexpr int E_CONST = 20000;
// coarse buckets: v>>9 (196), e>>7 (157); fine ordering inside k_build:
// v-lists grouped by e>>11 (10 chunks of 2 MB Ycat), e-lists by v>>12 (25 chunks of 2 MB Xbi)
static constexpr int SH_V = 9, SUBD_V = 512;
static constexpr int SH_E = 7, SUBD_E = 128;
static constexpr int ECH = 11, NSUB_E = 10;
static constexpr int VCH = 12, NSUB_V = 25;
static constexpr int CHUNKA = 4096;

typedef unsigned short u16;
typedef __attribute__((ext_vector_type(4))) unsigned short u16x4;
typedef __attribute__((ext_vector_type(8))) unsigned short u16x8;
typedef __attribute__((ext_vector_type(8))) short bf16x8;
typedef __attribute__((ext_vector_type(4))) float f32x4;

static __device__ __forceinline__ float bf2f(u16 u) {
    union { unsigned int i; float f; } x;
    x.i = ((unsigned int)u) << 16;
    return x.f;
}
static __device__ __forceinline__ u16 f2bf(float f) {
    union { float f; unsigned int i; } x;
    x.f = f;
    unsigned int r = x.i + 0x7fffu + ((x.i >> 16) & 1u);
    return (u16)(r >> 16);
}

// ---------------- CSR build: coarse bucket sort + order-preserving per-bucket build ----------------

__global__ void k_hist2(const int* __restrict__ pv, const int* __restrict__ pe,
                        int* __restrict__ btot_v, int* __restrict__ btot_e, int P) {
    __shared__ int cv[256], ce[256];
    int tid = threadIdx.x;
    cv[tid] = 0; ce[tid] = 0;
    __syncthreads();
    int p0 = blockIdx.x * CHUNKA;
    #pragma unroll
    for (int j = 0; j < CHUNKA / 256; ++j) {
        int p = p0 + tid + j * 256;
        if (p < P) {
            atomicAdd(&cv[pv[p] >> SH_V], 1);
            atomicAdd(&ce[pe[p] >> SH_E], 1);
        }
    }
    __syncthreads();
    if (cv[tid]) atomicAdd(&btot_v[tid], cv[tid]);
    if (ce[tid]) atomicAdd(&btot_e[tid], ce[tid]);
}

// in-place exclusive scan, a[n]=total (single block)
__global__ void k_scan_small(int* __restrict__ a, int n) {
    __shared__ int wsum[16];
    __shared__ int carry_s;
    int tid = threadIdx.x;
    int lane = tid & 63;
    int w = tid >> 6;
    if (tid == 0) carry_s = 0;
    __syncthreads();
    for (int base = 0; base < n; base += 1024) {
        int i = base + tid;
        int v = (i < n) ? a[i] : 0;
        int x = v;
        #pragma unroll
        for (int off = 1; off < 64; off <<= 1) {
            int t = __shfl_up(x, off);
            if (lane >= off) x += t;
        }
        if (lane == 63) wsum[w] = x;
        __syncthreads();
        int woff = 0;
        for (int k = 0; k < w; ++k) woff += wsum[k];
        int carry = carry_s;
        if (i < n) a[i] = carry + woff + x - v;
        int tot = 0;
        for (int k = 0; k < 16; ++k) tot += wsum[k];
        __syncthreads();
        if (tid == 0) carry_s = carry + tot;
        __syncthreads();
    }
    if (tid == 0) a[n] = carry_s;
}

__global__ void k_scatter2way(const int* __restrict__ pv, const int* __restrict__ pe,
                              const int* __restrict__ bstart_v, const int* __restrict__ bstart_e,
                              int* __restrict__ cur_v, int* __restrict__ cur_e,
                              uint2* __restrict__ sorted_v, uint2* __restrict__ sorted_e, int P) {
    __shared__ int cv[256], ce[256], posv[256], pose[256];
    int tid = threadIdx.x;
    cv[tid] = 0; ce[tid] = 0;
    __syncthreads();
    int p0 = blockIdx.x * CHUNKA;
    int kv[CHUNKA / 256], ke[CHUNKA / 256];
    #pragma unroll
    for (int j = 0; j < CHUNKA / 256; ++j) {
        int p = p0 + tid + j * 256;
        if (p < P) {
            kv[j] = pv[p];
            ke[j] = pe[p];
            atomicAdd(&cv[kv[j] >> SH_V], 1);
            atomicAdd(&ce[ke[j] >> SH_E], 1);
        } else {
            kv[j] = -1;
            ke[j] = -1;
        }
    }
    __syncthreads();
    if (cv[tid]) posv[tid] = bstart_v[tid] + atomicAdd(&cur_v[tid], cv[tid]);
    if (ce[tid]) pose[tid] = bstart_e[tid] + atomicAdd(&cur_e[tid], ce[tid]);
    __syncthreads();
    #pragma unroll
    for (int j = 0; j < CHUNKA / 256; ++j) {
        if (kv[j] >= 0) {
            int iv = atomicAdd(&posv[kv[j] >> SH_V], 1);
            sorted_v[iv] = make_uint2((unsigned)kv[j], (unsigned)ke[j]);
            int ie = atomicAdd(&pose[ke[j] >> SH_E], 1);
            sorted_e[ie] = make_uint2((unsigned)ke[j], (unsigned)kv[j]);
        }
    }
}

// order-preserving per-bucket CSR build: fine key = loc*NSUB + (payload>>CSH).
// Entries of each key end up grouped by ascending payload-chunk -> temporal locality
// in the gather kernels, with ZERO change to their code.
template <int SUBD, int SH, int NSUB, int CSH>
__global__ __launch_bounds__(256) void k_build_ord(const uint2* __restrict__ sorted,
                                                   const int* __restrict__ bstart,
                                                   int* __restrict__ start_out,
                                                   int* __restrict__ deg_out,
                                                   int* __restrict__ csr_out, int D) {
    constexpr int NK2 = SUBD * NSUB;
    constexpr int STRIP = (NK2 + 255) / 256;
    __shared__ int cnt[NK2];
    __shared__ int wsum[4];
    int b = blockIdx.x;
    int tid = threadIdx.x;
    int base_key = b << SH;
    int s0 = bstart[b];
    int cntN = bstart[b + 1] - s0;
    for (int k = tid; k < NK2; k += 256) cnt[k] = 0;
    __syncthreads();
    for (int i = tid; i < cntN; i += 256) {
        uint2 pr = sorted[s0 + i];
        int k2 = ((int)pr.x - base_key) * NSUB + ((int)pr.y >> CSH);
        atomicAdd(&cnt[k2], 1);
    }
    __syncthreads();
    // in-LDS exclusive scan of cnt[NK2]
    int local[STRIP];
    int sum = 0;
    int t0 = tid * STRIP;
    #pragma unroll
    for (int j = 0; j < STRIP; ++j) {
        int idx = t0 + j;
        local[j] = (idx < NK2) ? cnt[idx] : 0;
        sum += local[j];
    }
    int lane = tid & 63, w = tid >> 6;
    int x = sum;
    #pragma unroll
    for (int off = 1; off < 64; off <<= 1) {
        int t = __shfl_up(x, off);
        if (lane >= off) x += t;
    }
    if (lane == 63) wsum[w] = x;
    __syncthreads();
    int woff = 0;
    for (int k = 0; k < w; ++k) woff += wsum[k];
    int run = woff + x - sum;
    __syncthreads();
    #pragma unroll
    for (int j = 0; j < STRIP; ++j) {
        int idx = t0 + j;
        if (idx < NK2) {
            int tmp = local[j];
            cnt[idx] = run;
            run += tmp;
        }
    }
    __syncthreads();
    for (int loc = tid; loc < SUBD; loc += 256) {
        int key = base_key + loc;
        if (key < D) {
            int st = cnt[loc * NSUB];
            int en = (loc == SUBD - 1) ? cntN : cnt[(loc + 1) * NSUB];
            start_out[key] = s0 + st;
            deg_out[key] = en - st;
        }
    }
    __syncthreads();
    for (int i = tid; i < cntN; i += 256) {
        uint2 pr = sorted[s0 + i];
        int k2 = ((int)pr.x - base_key) * NSUB + ((int)pr.y >> CSH);
        int idx = atomicAdd(&cnt[k2], 1);
        csr_out[s0 + idx] = (int)pr.y;
    }
}

// ---------------- weight prep ----------------

__global__ void k_wav(const float* __restrict__ W1, const float* __restrict__ b1,
                      const float* __restrict__ av1, float* __restrict__ wav,
                      float* __restrict__ bav) {
    int h = blockIdx.x;
    int k = threadIdx.x;
    float s = 0.f;
    for (int j = 0; j < DH; ++j) s += W1[(size_t)(h * DIN + k) * DH + j] * av1[h * DH + j];
    wav[h * DIN + k] = s;
    if (k == 0) {
        float t = 0.f;
        for (int j = 0; j < DH; ++j) t += b1[h * DH + j] * av1[h * DH + j];
        bav[h] = t;
    }
}

__global__ void k_build_wcatT(const float* __restrict__ W1, u16* __restrict__ WcatT) {
    int idx = blockIdx.x * 256 + threadIdx.x;
    if (idx >= 256 * DIN) return;
    int c = idx >> 7, k = idx & 127;
    int h = c >> 6, j = c & 63;
    WcatT[c * DIN + k] = f2bf(W1[((size_t)h * DIN + k) * DH + j]);
}

__global__ void k_build_w2T(const float* __restrict__ W2, u16* __restrict__ W2T) {
    int idx = blockIdx.x * 256 + threadIdx.x;
    if (idx >= 48 * DCAT) return;
    int c = idx >> 9, k = idx & 511;
    float v = (c < NC) ? W2[(size_t)k * NC + c] : 0.f;
    W2T[c * DCAT + k] = f2bf(v);
}

// ---------------- conversion + node attention term (layer 1), both inputs ----------------
__global__ void k_conv(const float* __restrict__ X0, const float* __restrict__ X1,
                       const float* __restrict__ wav, const float* __restrict__ bav,
                       u16* __restrict__ Xbi, float* __restrict__ sv8, int N) {
    int wave = (blockIdx.x * blockDim.x + threadIdx.x) >> 6;
    int lane = threadIdx.x & 63;
    if (wave >= N) return;
    int xz = blockIdx.y;
    const float* X = xz ? X1 : X0;
    float2 a = *(const float2*)(X + (size_t)wave * DIN + lane * 2);
    unsigned int packed = (unsigned int)f2bf(a.x) | ((unsigned int)f2bf(a.y) << 16);
    *(unsigned int*)(Xbi + (size_t)wave * 256 + xz * 128 + lane * 2) = packed;
    float s[NH];
    #pragma unroll
    for (int h = 0; h < NH; ++h) {
        float2 wv = *(const float2*)(wav + h * DIN + lane * 2);
        float t = a.x * wv.x + a.y * wv.y;
        #pragma unroll
        for (int off = 32; off >= 1; off >>= 1) t += __shfl_xor(t, off);
        s[h] = t;
    }
    if (lane == 0) {
        #pragma unroll
        for (int h = 0; h < NH; ++h) sv8[(size_t)wave * 8 + h * 2 + xz] = s[h] + bav[h];
    }
}

// ---------------- edge mean (bf16, D=128), both inputs, unroll-3 pipelined ----------------
__global__ void k_edge_mean1(const u16* __restrict__ Xbi, const int* __restrict__ start_e,
                             const int* __restrict__ deg_e, const int* __restrict__ csr_e_v,
                             u16* __restrict__ Xbar0, u16* __restrict__ Xbar1, int E) {
    int wave = (blockIdx.x * blockDim.x + threadIdx.x) >> 6;
    int lane = threadIdx.x & 63;
    if (wave >= E) return;
    int s = start_e[wave], t = s + deg_e[wave];
    int q = lane >> 4, c = lane & 15;
    float a0[8], a1[8];
    #pragma unroll
    for (int j = 0; j < 8; ++j) { a0[j] = 0.f; a1[j] = 0.f; }
    int i = s + q;
    u16x8 y0A = {0}, y1A = {0}, y0B = {0}, y1B = {0}, y0C = {0}, y1C = {0};
#define EM1_LOAD(Y0, Y1, IDX) { int v_ = csr_e_v[IDX]; \
        const u16* yp_ = Xbi + (size_t)v_ * 256 + c * 8; \
        Y0 = *(const u16x8*)yp_; Y1 = *(const u16x8*)(yp_ + 128); }
#define EM1_CONSUME(Y0, Y1) { \
        _Pragma("unroll") \
        for (int j = 0; j < 8; ++j) { a0[j] += bf2f(Y0[j]); a1[j] += bf2f(Y1[j]); } }
    if (i < t) EM1_LOAD(y0A, y1A, i);
    if (i + 4 < t) EM1_LOAD(y0B, y1B, i + 4);
    if (i + 8 < t) EM1_LOAD(y0C, y1C, i + 8);
    for (; i + 8 < t; i += 12) {
        EM1_CONSUME(y0A, y1A);
        if (i + 12 < t) EM1_LOAD(y0A, y1A, i + 12);
        EM1_CONSUME(y0B, y1B);
        if (i + 16 < t) EM1_LOAD(y0B, y1B, i + 16);
        EM1_CONSUME(y0C, y1C);
        if (i + 20 < t) EM1_LOAD(y0C, y1C, i + 20);
    }
    if (i < t) EM1_CONSUME(y0A, y1A);
    if (i + 4 < t) EM1_CONSUME(y0B, y1B);
#undef EM1_LOAD
#undef EM1_CONSUME
    #pragma unroll
    for (int j = 0; j < 8; ++j) {
        a0[j] += __shfl_xor(a0[j], 16);
        a0[j] += __shfl_xor(a0[j], 32);
        a1[j] += __shfl_xor(a1[j], 16);
        a1[j] += __shfl_xor(a1[j], 32);
    }
    int deg = t - s;
    float inv = 1.f / (float)(deg > 1 ? deg : 1);
    if (q == 0) {
        u16x8 r0, r1;
        #pragma unroll
        for (int j = 0; j < 8; ++j) { r0[j] = f2bf(a0[j] * inv); r1[j] = f2bf(a1[j] * inv); }
        *(u16x8*)(Xbar0 + (size_t)wave * DIN + c * 8) = r0;
        *(u16x8*)(Xbar1 + (size_t)wave * DIN + c * 8) = r1;
    }
}

// ---------------- MFMA GEMM with fused row-dot epilogue ----------------
template <int KDIM, int NTILES, int DOTMODE>
__global__ __launch_bounds__(256) void k_gemm_mfma(const u16* __restrict__ A0,
                                                   const u16* __restrict__ A1, int M,
                                                   const u16* __restrict__ Bt,
                                                   const float* __restrict__ bias,
                                                   u16* __restrict__ out0, u16* __restrict__ out1,
                                                   int ldo, int ncols,
                                                   const float* __restrict__ dvec,
                                                   float* __restrict__ dout) {
    constexpr int LDB = KDIM + 8;
    __shared__ u16 Bs[NTILES * 16 * LDB];
    const u16* A = blockIdx.z ? A1 : A0;
    u16* out = blockIdx.z ? out1 : out0;
    int tid = threadIdx.x;
    int colbase = blockIdx.y * NTILES * 16;
    const u16* Btblk = Bt + (size_t)colbase * KDIM;
    for (int idx = tid * 4; idx < NTILES * 16 * KDIM; idx += 256 * 4) {
        int c = idx / KDIM, k = idx % KDIM;
        *(u16x4*)&Bs[c * LDB + k] = *(const u16x4*)(Btblk + c * KDIM + k);
    }
    __syncthreads();
    int w = tid >> 6, lane = tid & 63;
    int r0 = blockIdx.x * 64 + w * 16;
    int arow = r0 + (lane & 15);
    bool avalid = arow < M;
    const u16* ap = A + (size_t)arow * KDIM + (lane >> 4) * 8;
    f32x4 acc[NTILES];
    #pragma unroll
    for (int nt = 0; nt < NTILES; ++nt) acc[nt] = (f32x4){0.f, 0.f, 0.f, 0.f};
    #pragma unroll
    for (int k0 = 0; k0 < KDIM; k0 += 32) {
        bf16x8 a = (bf16x8)(short)0;
        if (avalid) a = *(const bf16x8*)(ap + k0);
        #pragma unroll
        for (int nt = 0; nt < NTILES; ++nt) {
            bf16x8 b = *(const bf16x8*)&Bs[(nt * 16 + (lane & 15)) * LDB + k0 + (lane >> 4) * 8];
            acc[nt] = __builtin_amdgcn_mfma_f32_16x16x32_bf16(a, b, acc[nt], 0, 0, 0);
        }
    }
    #pragma unroll
    for (int j = 0; j < 4; ++j) {
        int row = r0 + (lane >> 4) * 4 + j;
        float pA = 0.f, pB = 0.f;
        #pragma unroll
        for (int nt = 0; nt < NTILES; ++nt) {
            int col = colbase + nt * 16 + (lane & 15);
            bool cok = col < ncols;
            float val = cok ? acc[nt][j] + bias[col] : 0.f;
            if (DOTMODE == 1) {
                float dv = dvec[col];
                if (nt < NTILES / 2) pA += val * dv; else pB += val * dv;
            } else if (DOTMODE == 2) {
                pA += cok ? val * dvec[col] : 0.f;
            }
            if (row < M && cok) out[(size_t)row * ldo + col] = f2bf(val);
        }
        if (DOTMODE) {
            pA += __shfl_xor(pA, 1);
            pA += __shfl_xor(pA, 2);
            pA += __shfl_xor(pA, 4);
            pA += __shfl_xor(pA, 8);
            if (DOTMODE == 1) {
                pB += __shfl_xor(pB, 1);
                pB += __shfl_xor(pB, 2);
                pB += __shfl_xor(pB, 4);
                pB += __shfl_xor(pB, 8);
            }
            if ((lane & 15) == 0 && row < M) {
                if (DOTMODE == 1) {
                    int hbase = blockIdx.y * 2;
                    int z = blockIdx.z;
                    dout[(size_t)row * 8 + hbase * 2 + z] = pA;
                    dout[(size_t)row * 8 + (hbase + 1) * 2 + z] = pB;
                } else {
                    dout[row] = pA;
                }
            }
        }
    }
}

// ---------------- fused node pass (layer 1), both inputs, simple loop ----------------
__global__ void k_node_pass1(const u16* __restrict__ Ycat, const float* __restrict__ se8,
                             const float* __restrict__ sv8, const int* __restrict__ start_v,
                             const int* __restrict__ deg_v, const int* __restrict__ csr_v_e,
                             u16* __restrict__ hbuf, int N) {
    int wave = (blockIdx.x * blockDim.x + threadIdx.x) >> 6;
    int lane = threadIdx.x & 63;
    if (wave >= N) return;
    int p0 = start_v[wave], p1 = p0 + deg_v[wave];
    int g = lane >> 5;
    int c = lane & 31;
    int h = c >> 3;
    u16* orow = hbuf + (size_t)wave * DCAT + c * 8;
    if (p1 == p0) {
        if (g == 0) {
            u16x8 z8 = {0, 0, 0, 0, 0, 0, 0, 0};
            *(u16x8*)orow = z8;
            *(u16x8*)(orow + 256) = z8;
        }
        return;
    }
    float sv0 = sv8[(size_t)wave * 8 + h * 2];
    float sv1 = sv8[(size_t)wave * 8 + h * 2 + 1];
    float den0 = 0.f, den1 = 0.f;
    float a0[8], a1[8];
    #pragma unroll
    for (int j = 0; j < 8; ++j) { a0[j] = 0.f; a1[j] = 0.f; }
    for (int i = p0 + g; i < p1; i += 2) {
        int e = csr_v_e[i];
        float2 s2 = *(const float2*)(se8 + e * 8 + h * 2);
        float x0 = s2.x + sv0;
        float x1 = s2.y + sv1;
        x0 = fmaxf(x0, 0.2f * x0);
        x1 = fmaxf(x1, 0.2f * x1);
        float e0 = __expf(x0);
        float e1 = __expf(x1);
        den0 += e0;
        den1 += e1;
        const u16* yp = Ycat + (size_t)e * 512 + c * 8;
        u16x8 q0 = *(const u16x8*)yp;
        u16x8 q1 = *(const u16x8*)(yp + 256);
        #pragma unroll
        for (int j = 0; j < 8; ++j) { a0[j] += e0 * bf2f(q0[j]); a1[j] += e1 * bf2f(q1[j]); }
    }
    den0 += __shfl_xor(den0, 32);
    den1 += __shfl_xor(den1, 32);
    #pragma unroll
    for (int j = 0; j < 8; ++j) {
        a0[j] += __shfl_xor(a0[j], 32);
        a1[j] += __shfl_xor(a1[j], 32);
    }
    float i0 = 1.f / den0, i1 = 1.f / den1;
    u16x8 r0, r1;
    #pragma unroll
    for (int j = 0; j < 8; ++j) {
        float o0 = a0[j] * i0;
        float o1 = a1[j] * i1;
        o0 = o0 > 0.f ? o0 : __expf(o0) - 1.f;
        o1 = o1 > 0.f ? o1 : __expf(o1) - 1.f;
        r0[j] = f2bf(o0);
        r1[j] = f2bf(o1);
    }
    if (g == 0) {
        *(u16x8*)orow = r0;
        *(u16x8*)(orow + 256) = r1;
    }
}

// ---------------- layer 2 small kernels ----------------

__global__ void k_edge_mean2(const u16* __restrict__ Xp2b, const int* __restrict__ start_e,
                             const int* __restrict__ deg_ea, const int* __restrict__ csr_e_v,
                             u16* __restrict__ Y2b, const float* __restrict__ ae2,
                             float* __restrict__ se2, int E) {
    int wave = (blockIdx.x * blockDim.x + threadIdx.x) >> 6;
    int lane = threadIdx.x & 63;
    if (wave >= E) return;
    int s = start_e[wave], t = s + deg_ea[wave];
    int g = lane >> 4, c = lane & 15;
    bool act = c < 10;
    float acc[4];
    #pragma unroll
    for (int j = 0; j < 4; ++j) acc[j] = 0.f;
    for (int i = s + g; i < t; i += 4) {
        int v = csr_e_v[i];
        if (act) {
            u16x4 y = *(const u16x4*)(Xp2b + (size_t)v * NC + c * 4);
            acc[0] += bf2f(y.x);
            acc[1] += bf2f(y.y);
            acc[2] += bf2f(y.z);
            acc[3] += bf2f(y.w);
        }
    }
    #pragma unroll
    for (int j = 0; j < 4; ++j) {
        acc[j] += __shfl_xor(acc[j], 16);
        acc[j] += __shfl_xor(acc[j], 32);
    }
    int deg = t - s;
    float inv = 1.f / (float)(deg > 1 ? deg : 1);
    float p = 0.f;
    if (act) {
        float4 ae = *(const float4*)(ae2 + c * 4);
        float y0 = acc[0] * inv, y1 = acc[1] * inv, y2 = acc[2] * inv, y3 = acc[3] * inv;
        p = y0 * ae.x + y1 * ae.y + y2 * ae.z + y3 * ae.w;
        if (g == 0) {
            u16x4 r = {f2bf(y0), f2bf(y1), f2bf(y2), f2bf(y3)};
            *(u16x4*)(Y2b + (size_t)wave * NC + c * 4) = r;
        }
    }
    #pragma unroll
    for (int off = 8; off >= 1; off >>= 1) p += __shfl_xor(p, off);
    if (lane == 0) se2[wave] = p;
}

__global__ void k_node_pass2(const u16* __restrict__ Y2b, const float* __restrict__ se2,
                             const float* __restrict__ sv2, const int* __restrict__ start_v,
                             const int* __restrict__ deg_va, const int* __restrict__ csr_v_e,
                             float* __restrict__ out, int N) {
    int wave = (blockIdx.x * blockDim.x + threadIdx.x) >> 6;
    int lane = threadIdx.x & 63;
    if (wave >= N) return;
    int s = start_v[wave], t = s + deg_va[wave];
    int g = lane >> 4, c = lane & 15;
    bool act = c < 10;
    float* orow = out + (size_t)wave * NC;
    if (t == s) {
        if (g == 0 && act) *(float4*)(orow + c * 4) = make_float4(0.f, 0.f, 0.f, 0.f);
        return;
    }
    float svv = sv2[wave];
    float den = 0.f;
    float acc[4];
    #pragma unroll
    for (int j = 0; j < 4; ++j) acc[j] = 0.f;
    for (int i = s + g; i < t; i += 4) {
        int e = csr_v_e[i];
        float x = se2[e] + svv;
        x = fmaxf(x, 0.2f * x);
        float ex = __expf(x);
        den += ex;
        if (act) {
            u16x4 y = *(const u16x4*)(Y2b + (size_t)e * NC + c * 4);
            acc[0] += ex * bf2f(y.x);
            acc[1] += ex * bf2f(y.y);
            acc[2] += ex * bf2f(y.z);
            acc[3] += ex * bf2f(y.w);
        }
    }
    den += __shfl_xor(den, 16);
    den += __shfl_xor(den, 32);
    #pragma unroll
    for (int j = 0; j < 4; ++j) {
        acc[j] += __shfl_xor(acc[j], 16);
        acc[j] += __shfl_xor(acc[j], 32);
    }
    if (g == 0 && act) {
        float inv = 1.f / den;
        float4 o;
        float* op = &o.x;
        #pragma unroll
        for (int j = 0; j < 4; ++j) {
            float v = acc[j] * inv;
            op[j] = v > 0.f ? v : __expf(v) - 1.f;
        }
        *(float4*)(orow + c * 4) = o;
    }
}

// ---------------- launcher ----------------
extern "C" void kernel_launch(void* const* d_in, const int* in_sizes, int n_in,
                              void* d_out, int out_size, void* d_ws, size_t ws_size,
                              hipStream_t stream) {
    const float* x0 = (const float*)d_in[0];
    const float* x1 = (const float*)d_in[1];
    const float* W1 = (const float*)d_in[2];
    const float* b1 = (const float*)d_in[3];
    const float* ae1 = (const float*)d_in[4];
    const float* av1 = (const float*)d_in[5];
    const float* W2 = (const float*)d_in[6];
    const float* b2 = (const float*)d_in[7];
    const float* ae2 = (const float*)d_in[8];
    const float* av2 = (const float*)d_in[9];
    const int* pe = (const int*)d_in[10];
    const int* pv = (const int*)d_in[11];

    const int N = in_sizes[0] / DIN;  // 100000
    const int P = in_sizes[10];       // 1600000
    const int E = E_CONST;            // 20000
    const int NBKT_V = (N + SUBD_V - 1) / SUBD_V;   // 196
    const int NBKT_E = (E + SUBD_E - 1) / SUBD_E;   // 157

    char* base = (char*)d_ws;
    auto alloc = [&](size_t bytes) -> void* {
        void* p = (void*)base;
        base += (bytes + 255) & ~(size_t)255;
        return p;
    };
    u16* Xbi = (u16*)alloc((size_t)N * 256 * 2);
    u16* hbuf = (u16*)alloc((size_t)N * DCAT * 2);
    u16* Xbar0 = (u16*)alloc((size_t)E * DIN * 2);
    u16* Xbar1 = (u16*)alloc((size_t)E * DIN * 2);
    u16* Ycat = (u16*)alloc((size_t)E * 512 * 2);
    u16* Xp2b = (u16*)alloc((size_t)N * NC * 2);
    u16* Y2b = (u16*)alloc((size_t)E * NC * 2);
    float* se8 = (float*)alloc((size_t)E * 8 * 4);
    float* se2 = (float*)alloc((size_t)E * 4);
    float* sv8 = (float*)alloc((size_t)N * 8 * 4);
    float* sv2 = (float*)alloc((size_t)N * 4);
    float* wav = (float*)alloc((size_t)NH * DIN * 4);
    float* bav = (float*)alloc((size_t)NH * 4);
    u16* WcatT = (u16*)alloc((size_t)256 * DIN * 2);
    u16* W2T = (u16*)alloc((size_t)48 * DCAT * 2);
    uint2* sorted_v = (uint2*)alloc((size_t)P * 8);
    uint2* sorted_e = (uint2*)alloc((size_t)P * 8);
    int* start_v = (int*)alloc((size_t)N * 4);
    int* deg_v = (int*)alloc((size_t)N * 4);
    int* start_e = (int*)alloc((size_t)E * 4);
    int* deg_e = (int*)alloc((size_t)E * 4);
    int* csr_v_e = (int*)alloc((size_t)P * 4);
    int* csr_e_v = (int*)alloc((size_t)P * 4);
    char* zstart = base;
    int* bstart_v = (int*)alloc((size_t)(NBKT_V + 1) * 4);
    int* bstart_e = (int*)alloc((size_t)(NBKT_E + 1) * 4);
    int* cur_v = (int*)alloc((size_t)256 * 4);
    int* cur_e = (int*)alloc((size_t)256 * 4);
    size_t zbytes = (size_t)(base - zstart);

    if ((size_t)(base - (char*)d_ws) > ws_size) return;

    hipMemsetAsync(zstart, 0, zbytes, stream);

    dim3 b256(256);
    int nA = (P + CHUNKA - 1) / CHUNKA;   // 391
    k_hist2<<<nA, b256, 0, stream>>>(pv, pe, bstart_v, bstart_e, P);
    k_scan_small<<<1, 1024, 0, stream>>>(bstart_v, NBKT_V);
    k_scan_small<<<1, 1024, 0, stream>>>(bstart_e, NBKT_E);
    k_scatter2way<<<nA, b256, 0, stream>>>(pv, pe, bstart_v, bstart_e, cur_v, cur_e,
                                           sorted_v, sorted_e, P);
    k_build_ord<SUBD_V, SH_V, NSUB_E, ECH><<<NBKT_V, b256, 0, stream>>>(sorted_v, bstart_v,
                                                                        start_v, deg_v,
                                                                        csr_v_e, N);
    k_build_ord<SUBD_E, SH_E, NSUB_V, VCH><<<NBKT_E, b256, 0, stream>>>(sorted_e, bstart_e,
                                                                        start_e, deg_e,
                                                                        csr_e_v, E);

    k_wav<<<NH, DIN, 0, stream>>>(W1, b1, av1, wav, bav);
    k_build_wcatT<<<(256 * DIN + 255) / 256, b256, 0, stream>>>(W1, WcatT);
    k_build_w2T<<<(48 * DCAT + 255) / 256, b256, 0, stream>>>(W2, W2T);

    int gN4 = (N + 3) / 4;
    int gE4 = (E + 3) / 4;
    dim3 gconv(gN4, 2);
    k_conv<<<gconv, b256, 0, stream>>>(x0, x1, wav, bav, Xbi, sv8, N);

    k_edge_mean1<<<gE4, b256, 0, stream>>>(Xbi, start_e, deg_e, csr_e_v, Xbar0, Xbar1, E);
    dim3 g1((E + 63) / 64, 2, 2);
    k_gemm_mfma<DIN, 8, 1><<<g1, b256, 0, stream>>>(Xbar0, Xbar1, E, WcatT, b1,
                                                    Ycat, Ycat + 256, 512, 256, ae1, se8);
    k_node_pass1<<<gN4, b256, 0, stream>>>(Ycat, se8, sv8, start_v, deg_v, csr_v_e, hbuf, N);

    dim3 g2((N + 63) / 64, 1, 1);
    k_gemm_mfma<DCAT, 3, 2><<<g2, b256, 0, stream>>>(hbuf, hbuf, N, W2T, b2, Xp2b, Xp2b,
                                                     NC, NC, av2, sv2);
    k_edge_mean2<<<gE4, b256, 0, stream>>>(Xp2b, start_e, deg_e, csr_e_v, Y2b, ae2, se2, E);
    k_node_pass2<<<gN4, b256, 0, stream>>>(Y2b, se2, sv2, start_v, deg_v, csr_v_e,
                                           (float*)d_out, N);
}

// Round 11
// 642.466 us; speedup vs baseline: 1.1240x; 1.0371x over previous
//
#include <hip/hip_runtime.h>
#include <cstdint>
#include <cstddef>

// N=100000, E=20000, P=1600000, din=128, dh=64, H=4, DCAT=512, C=40
static constexpr int DIN = 128;
static constexpr int DH = 64;
static constexpr int NH = 4;
static constexpr int DCAT = 512;
static constexpr int NC = 40;
static constexpr int E_CONST = 20000;
static constexpr int SH_V = 9, SUBD_V = 512;
static constexpr int SH_E = 7, SUBD_E = 128;
static constexpr int ECH = 11, NSUB_E = 10;
static constexpr int VCH = 12, NSUB_V = 25;
static constexpr int CHUNKA = 4096;

typedef unsigned short u16;
typedef __attribute__((ext_vector_type(4))) unsigned short u16x4;
typedef __attribute__((ext_vector_type(8))) unsigned short u16x8;
typedef __attribute__((ext_vector_type(8))) short bf16x8;
typedef __attribute__((ext_vector_type(4))) float f32x4;

static __device__ __forceinline__ float bf2f(u16 u) {
    union { unsigned int i; float f; } x;
    x.i = ((unsigned int)u) << 16;
    return x.f;
}
static __device__ __forceinline__ u16 f2bf(float f) {
    union { float f; unsigned int i; } x;
    x.f = f;
    unsigned int r = x.i + 0x7fffu + ((x.i >> 16) & 1u);
    return (u16)(r >> 16);
}

// ---------------- CSR build: coarse bucket sort + order-preserving per-bucket build ----------------

__global__ void k_hist2(const int* __restrict__ pv, const int* __restrict__ pe,
                        int* __restrict__ btot_v, int* __restrict__ btot_e, int P) {
    __shared__ int cv[256], ce[256];
    int tid = threadIdx.x;
    cv[tid] = 0; ce[tid] = 0;
    __syncthreads();
    int p0 = blockIdx.x * CHUNKA;
    #pragma unroll
    for (int j = 0; j < CHUNKA / 256; ++j) {
        int p = p0 + tid + j * 256;
        if (p < P) {
            atomicAdd(&cv[pv[p] >> SH_V], 1);
            atomicAdd(&ce[pe[p] >> SH_E], 1);
        }
    }
    __syncthreads();
    if (cv[tid]) atomicAdd(&btot_v[tid], cv[tid]);
    if (ce[tid]) atomicAdd(&btot_e[tid], ce[tid]);
}

// in-place exclusive scan, a[n]=total (single block)
__global__ void k_scan_small(int* __restrict__ a, int n) {
    __shared__ int wsum[16];
    __shared__ int carry_s;
    int tid = threadIdx.x;
    int lane = tid & 63;
    int w = tid >> 6;
    if (tid == 0) carry_s = 0;
    __syncthreads();
    for (int base = 0; base < n; base += 1024) {
        int i = base + tid;
        int v = (i < n) ? a[i] : 0;
        int x = v;
        #pragma unroll
        for (int off = 1; off < 64; off <<= 1) {
            int t = __shfl_up(x, off);
            if (lane >= off) x += t;
        }
        if (lane == 63) wsum[w] = x;
        __syncthreads();
        int woff = 0;
        for (int k = 0; k < w; ++k) woff += wsum[k];
        int carry = carry_s;
        if (i < n) a[i] = carry + woff + x - v;
        int tot = 0;
        for (int k = 0; k < 16; ++k) tot += wsum[k];
        __syncthreads();
        if (tid == 0) carry_s = carry + tot;
        __syncthreads();
    }
    if (tid == 0) a[n] = carry_s;
}

__global__ void k_scatter2way(const int* __restrict__ pv, const int* __restrict__ pe,
                              const int* __restrict__ bstart_v, const int* __restrict__ bstart_e,
                              int* __restrict__ cur_v, int* __restrict__ cur_e,
                              uint2* __restrict__ sorted_v, uint2* __restrict__ sorted_e, int P) {
    __shared__ int cv[256], ce[256], posv[256], pose[256];
    int tid = threadIdx.x;
    cv[tid] = 0; ce[tid] = 0;
    __syncthreads();
    int p0 = blockIdx.x * CHUNKA;
    int kv[CHUNKA / 256], ke[CHUNKA / 256];
    #pragma unroll
    for (int j = 0; j < CHUNKA / 256; ++j) {
        int p = p0 + tid + j * 256;
        if (p < P) {
            kv[j] = pv[p];
            ke[j] = pe[p];
            atomicAdd(&cv[kv[j] >> SH_V], 1);
            atomicAdd(&ce[ke[j] >> SH_E], 1);
        } else {
            kv[j] = -1;
            ke[j] = -1;
        }
    }
    __syncthreads();
    if (cv[tid]) posv[tid] = bstart_v[tid] + atomicAdd(&cur_v[tid], cv[tid]);
    if (ce[tid]) pose[tid] = bstart_e[tid] + atomicAdd(&cur_e[tid], ce[tid]);
    __syncthreads();
    #pragma unroll
    for (int j = 0; j < CHUNKA / 256; ++j) {
        if (kv[j] >= 0) {
            int iv = atomicAdd(&posv[kv[j] >> SH_V], 1);
            sorted_v[iv] = make_uint2((unsigned)kv[j], (unsigned)ke[j]);
            int ie = atomicAdd(&pose[ke[j] >> SH_E], 1);
            sorted_e[ie] = make_uint2((unsigned)ke[j], (unsigned)kv[j]);
        }
    }
}

// order-preserving per-bucket CSR build: fine key = loc*NSUB + (payload>>CSH).
template <int SUBD, int SH, int NSUB, int CSH>
__global__ __launch_bounds__(256) void k_build_ord(const uint2* __restrict__ sorted,
                                                   const int* __restrict__ bstart,
                                                   int* __restrict__ start_out,
                                                   int* __restrict__ deg_out,
                                                   int* __restrict__ csr_out, int D) {
    constexpr int NK2 = SUBD * NSUB;
    constexpr int STRIP = (NK2 + 255) / 256;
    __shared__ int cnt[NK2];
    __shared__ int wsum[4];
    int b = blockIdx.x;
    int tid = threadIdx.x;
    int base_key = b << SH;
    int s0 = bstart[b];
    int cntN = bstart[b + 1] - s0;
    for (int k = tid; k < NK2; k += 256) cnt[k] = 0;
    __syncthreads();
    for (int i = tid; i < cntN; i += 256) {
        uint2 pr = sorted[s0 + i];
        int k2 = ((int)pr.x - base_key) * NSUB + ((int)pr.y >> CSH);
        atomicAdd(&cnt[k2], 1);
    }
    __syncthreads();
    int local[STRIP];
    int sum = 0;
    int t0 = tid * STRIP;
    #pragma unroll
    for (int j = 0; j < STRIP; ++j) {
        int idx = t0 + j;
        local[j] = (idx < NK2) ? cnt[idx] : 0;
        sum += local[j];
    }
    int lane = tid & 63, w = tid >> 6;
    int x = sum;
    #pragma unroll
    for (int off = 1; off < 64; off <<= 1) {
        int t = __shfl_up(x, off);
        if (lane >= off) x += t;
    }
    if (lane == 63) wsum[w] = x;
    __syncthreads();
    int woff = 0;
    for (int k = 0; k < w; ++k) woff += wsum[k];
    int run = woff + x - sum;
    __syncthreads();
    #pragma unroll
    for (int j = 0; j < STRIP; ++j) {
        int idx = t0 + j;
        if (idx < NK2) {
            int tmp = local[j];
            cnt[idx] = run;
            run += tmp;
        }
    }
    __syncthreads();
    for (int loc = tid; loc < SUBD; loc += 256) {
        int key = base_key + loc;
        if (key < D) {
            int st = cnt[loc * NSUB];
            int en = (loc == SUBD - 1) ? cntN : cnt[(loc + 1) * NSUB];
            start_out[key] = s0 + st;
            deg_out[key] = en - st;
        }
    }
    __syncthreads();
    for (int i = tid; i < cntN; i += 256) {
        uint2 pr = sorted[s0 + i];
        int k2 = ((int)pr.x - base_key) * NSUB + ((int)pr.y >> CSH);
        int idx = atomicAdd(&cnt[k2], 1);
        csr_out[s0 + idx] = (int)pr.y;
    }
}

// ---------------- weight prep ----------------

__global__ void k_wav(const float* __restrict__ W1, const float* __restrict__ b1,
                      const float* __restrict__ av1, float* __restrict__ wav,
                      float* __restrict__ bav) {
    int h = blockIdx.x;
    int k = threadIdx.x;
    float s = 0.f;
    for (int j = 0; j < DH; ++j) s += W1[(size_t)(h * DIN + k) * DH + j] * av1[h * DH + j];
    wav[h * DIN + k] = s;
    if (k == 0) {
        float t = 0.f;
        for (int j = 0; j < DH; ++j) t += b1[h * DH + j] * av1[h * DH + j];
        bav[h] = t;
    }
}

__global__ void k_build_wcatT(const float* __restrict__ W1, u16* __restrict__ WcatT) {
    int idx = blockIdx.x * 256 + threadIdx.x;
    if (idx >= 256 * DIN) return;
    int c = idx >> 7, k = idx & 127;
    int h = c >> 6, j = c & 63;
    WcatT[c * DIN + k] = f2bf(W1[((size_t)h * DIN + k) * DH + j]);
}

__global__ void k_build_w2T(const float* __restrict__ W2, u16* __restrict__ W2T) {
    int idx = blockIdx.x * 256 + threadIdx.x;
    if (idx >= 48 * DCAT) return;
    int c = idx >> 9, k = idx & 511;
    float v = (c < NC) ? W2[(size_t)k * NC + c] : 0.f;
    W2T[c * DCAT + k] = f2bf(v);
}

// ---------------- conversion + node attention term (layer 1), both inputs ----------------
// Xbi interleaved [N][2][128]; sv8 slice-major: sv8[(z*4+h)*N + n]
__global__ void k_conv(const float* __restrict__ X0, const float* __restrict__ X1,
                       const float* __restrict__ wav, const float* __restrict__ bav,
                       u16* __restrict__ Xbi, float* __restrict__ sv8, int N) {
    int wave = (blockIdx.x * blockDim.x + threadIdx.x) >> 6;
    int lane = threadIdx.x & 63;
    if (wave >= N) return;
    int xz = blockIdx.y;
    const float* X = xz ? X1 : X0;
    float2 a = *(const float2*)(X + (size_t)wave * DIN + lane * 2);
    unsigned int packed = (unsigned int)f2bf(a.x) | ((unsigned int)f2bf(a.y) << 16);
    *(unsigned int*)(Xbi + (size_t)wave * 256 + xz * 128 + lane * 2) = packed;
    float s[NH];
    #pragma unroll
    for (int h = 0; h < NH; ++h) {
        float2 wv = *(const float2*)(wav + h * DIN + lane * 2);
        float t = a.x * wv.x + a.y * wv.y;
        #pragma unroll
        for (int off = 32; off >= 1; off >>= 1) t += __shfl_xor(t, off);
        s[h] = t;
    }
    if (lane == 0) {
        #pragma unroll
        for (int h = 0; h < NH; ++h) sv8[(size_t)(xz * 4 + h) * N + wave] = s[h] + bav[h];
    }
}

// ---------------- edge mean (bf16, D=128), both inputs, unroll-3 pipelined ----------------
__global__ void k_edge_mean1(const u16* __restrict__ Xbi, const int* __restrict__ start_e,
                             const int* __restrict__ deg_e, const int* __restrict__ csr_e_v,
                             u16* __restrict__ Xbar0, u16* __restrict__ Xbar1, int E) {
    int wave = (blockIdx.x * blockDim.x + threadIdx.x) >> 6;
    int lane = threadIdx.x & 63;
    if (wave >= E) return;
    int s = start_e[wave], t = s + deg_e[wave];
    int q = lane >> 4, c = lane & 15;
    float a0[8], a1[8];
    #pragma unroll
    for (int j = 0; j < 8; ++j) { a0[j] = 0.f; a1[j] = 0.f; }
    int i = s + q;
    u16x8 y0A = {0}, y1A = {0}, y0B = {0}, y1B = {0}, y0C = {0}, y1C = {0};
#define EM1_LOAD(Y0, Y1, IDX) { int v_ = csr_e_v[IDX]; \
        const u16* yp_ = Xbi + (size_t)v_ * 256 + c * 8; \
        Y0 = *(const u16x8*)yp_; Y1 = *(const u16x8*)(yp_ + 128); }
#define EM1_CONSUME(Y0, Y1) { \
        _Pragma("unroll") \
        for (int j = 0; j < 8; ++j) { a0[j] += bf2f(Y0[j]); a1[j] += bf2f(Y1[j]); } }
    if (i < t) EM1_LOAD(y0A, y1A, i);
    if (i + 4 < t) EM1_LOAD(y0B, y1B, i + 4);
    if (i + 8 < t) EM1_LOAD(y0C, y1C, i + 8);
    for (; i + 8 < t; i += 12) {
        EM1_CONSUME(y0A, y1A);
        if (i + 12 < t) EM1_LOAD(y0A, y1A, i + 12);
        EM1_CONSUME(y0B, y1B);
        if (i + 16 < t) EM1_LOAD(y0B, y1B, i + 16);
        EM1_CONSUME(y0C, y1C);
        if (i + 20 < t) EM1_LOAD(y0C, y1C, i + 20);
    }
    if (i < t) EM1_CONSUME(y0A, y1A);
    if (i + 4 < t) EM1_CONSUME(y0B, y1B);
#undef EM1_LOAD
#undef EM1_CONSUME
    #pragma unroll
    for (int j = 0; j < 8; ++j) {
        a0[j] += __shfl_xor(a0[j], 16);
        a0[j] += __shfl_xor(a0[j], 32);
        a1[j] += __shfl_xor(a1[j], 16);
        a1[j] += __shfl_xor(a1[j], 32);
    }
    int deg = t - s;
    float inv = 1.f / (float)(deg > 1 ? deg : 1);
    if (q == 0) {
        u16x8 r0, r1;
        #pragma unroll
        for (int j = 0; j < 8; ++j) { r0[j] = f2bf(a0[j] * inv); r1[j] = f2bf(a1[j] * inv); }
        *(u16x8*)(Xbar0 + (size_t)wave * DIN + c * 8) = r0;
        *(u16x8*)(Xbar1 + (size_t)wave * DIN + c * 8) = r1;
    }
}

// ---------------- MFMA GEMM with fused row-dot epilogue ----------------
// DOTMODE 1: per-head dots -> dout[(z*4+head)*M + row] (slice-major); 2: dout[row]
template <int KDIM, int NTILES, int DOTMODE>
__global__ __launch_bounds__(256) void k_gemm_mfma(const u16* __restrict__ A0,
                                                   const u16* __restrict__ A1, int M,
                                                   const u16* __restrict__ Bt,
                                                   const float* __restrict__ bias,
                                                   u16* __restrict__ out0, u16* __restrict__ out1,
                                                   int ldo, int ncols,
                                                   const float* __restrict__ dvec,
                                                   float* __restrict__ dout) {
    constexpr int LDB = KDIM + 8;
    __shared__ u16 Bs[NTILES * 16 * LDB];
    const u16* A = blockIdx.z ? A1 : A0;
    u16* out = blockIdx.z ? out1 : out0;
    int tid = threadIdx.x;
    int colbase = blockIdx.y * NTILES * 16;
    const u16* Btblk = Bt + (size_t)colbase * KDIM;
    for (int idx = tid * 4; idx < NTILES * 16 * KDIM; idx += 256 * 4) {
        int c = idx / KDIM, k = idx % KDIM;
        *(u16x4*)&Bs[c * LDB + k] = *(const u16x4*)(Btblk + c * KDIM + k);
    }
    __syncthreads();
    int w = tid >> 6, lane = tid & 63;
    int r0 = blockIdx.x * 64 + w * 16;
    int arow = r0 + (lane & 15);
    bool avalid = arow < M;
    const u16* ap = A + (size_t)arow * KDIM + (lane >> 4) * 8;
    f32x4 acc[NTILES];
    #pragma unroll
    for (int nt = 0; nt < NTILES; ++nt) acc[nt] = (f32x4){0.f, 0.f, 0.f, 0.f};
    #pragma unroll
    for (int k0 = 0; k0 < KDIM; k0 += 32) {
        bf16x8 a = (bf16x8)(short)0;
        if (avalid) a = *(const bf16x8*)(ap + k0);
        #pragma unroll
        for (int nt = 0; nt < NTILES; ++nt) {
            bf16x8 b = *(const bf16x8*)&Bs[(nt * 16 + (lane & 15)) * LDB + k0 + (lane >> 4) * 8];
            acc[nt] = __builtin_amdgcn_mfma_f32_16x16x32_bf16(a, b, acc[nt], 0, 0, 0);
        }
    }
    #pragma unroll
    for (int j = 0; j < 4; ++j) {
        int row = r0 + (lane >> 4) * 4 + j;
        float pA = 0.f, pB = 0.f;
        #pragma unroll
        for (int nt = 0; nt < NTILES; ++nt) {
            int col = colbase + nt * 16 + (lane & 15);
            bool cok = col < ncols;
            float val = cok ? acc[nt][j] + bias[col] : 0.f;
            if (DOTMODE == 1) {
                float dv = dvec[col];
                if (nt < NTILES / 2) pA += val * dv; else pB += val * dv;
            } else if (DOTMODE == 2) {
                pA += cok ? val * dvec[col] : 0.f;
            }
            if (row < M && cok) out[(size_t)row * ldo + col] = f2bf(val);
        }
        if (DOTMODE) {
            pA += __shfl_xor(pA, 1);
            pA += __shfl_xor(pA, 2);
            pA += __shfl_xor(pA, 4);
            pA += __shfl_xor(pA, 8);
            if (DOTMODE == 1) {
                pB += __shfl_xor(pB, 1);
                pB += __shfl_xor(pB, 2);
                pB += __shfl_xor(pB, 4);
                pB += __shfl_xor(pB, 8);
            }
            if ((lane & 15) == 0 && row < M) {
                if (DOTMODE == 1) {
                    int hbase = blockIdx.y * 2;
                    int z = blockIdx.z;
                    dout[(size_t)(z * 4 + hbase) * M + row] = pA;
                    dout[(size_t)(z * 4 + hbase + 1) * M + row] = pB;
                } else {
                    dout[row] = pA;
                }
            }
        }
    }
}

// ---------------- fused node pass (layer 1): XCD-column-sliced, group-per-node ----------------
// slice = blockIdx & 7 maps to one XCD (round-robin) and covers 64 cols (one input x head),
// i.e. a STATIC 2.56 MB slab of Ycat < 4 MB per-XCD L2 -> L2-resident regardless of timing.
// Wave = 8 groups x 8 lanes; group owns one node, walks its list serially; no reductions.
// se8/sv8 are slice-major so each slice's score array is small and line-efficient.
__global__ void k_node_pass1(const u16* __restrict__ Ycat, const float* __restrict__ se8,
                             const float* __restrict__ sv8, const int* __restrict__ start_v,
                             const int* __restrict__ deg_v, const int* __restrict__ csr_v_e,
                             u16* __restrict__ hbuf, int N, int E) {
    int bid = blockIdx.x;
    int s = bid & 7;
    int warp = threadIdx.x >> 6;
    int lane = threadIdx.x & 63;
    int g = lane >> 3, c = lane & 7;
    int node = (bid >> 3) * 32 + warp * 8 + g;
    if (node >= N) return;
    int p0 = start_v[node];
    int p1 = p0 + deg_v[node];
    float sv = sv8[(size_t)s * N + node];
    const float* seS = se8 + (size_t)s * E;
    const u16* ybase = Ycat + s * 64 + c * 8;
    float den = 0.f;
    float acc[8];
    #pragma unroll
    for (int j = 0; j < 8; ++j) acc[j] = 0.f;
    for (int i = p0; i < p1; ++i) {
        int e = csr_v_e[i];
        float x = seS[e] + sv;
        x = fmaxf(x, 0.2f * x);
        float ex = __expf(x);
        den += ex;
        u16x8 y = *(const u16x8*)(ybase + (size_t)e * 512);
        #pragma unroll
        for (int j = 0; j < 8; ++j) acc[j] += ex * bf2f(y[j]);
    }
    float inv = (p1 > p0) ? 1.f / den : 0.f;
    u16x8 r;
    #pragma unroll
    for (int j = 0; j < 8; ++j) {
        float o = acc[j] * inv;
        o = o > 0.f ? o : __expf(o) - 1.f;
        r[j] = f2bf(o);
    }
    *(u16x8*)(hbuf + (size_t)node * DCAT + s * 64 + c * 8) = r;
}

// ---------------- layer 2 small kernels ----------------

__global__ void k_edge_mean2(const u16* __restrict__ Xp2b, const int* __restrict__ start_e,
                             const int* __restrict__ deg_ea, const int* __restrict__ csr_e_v,
                             u16* __restrict__ Y2b, const float* __restrict__ ae2,
                             float* __restrict__ se2, int E) {
    int wave = (blockIdx.x * blockDim.x + threadIdx.x) >> 6;
    int lane = threadIdx.x & 63;
    if (wave >= E) return;
    int s = start_e[wave], t = s + deg_ea[wave];
    int g = lane >> 4, c = lane & 15;
    bool act = c < 10;
    float acc[4];
    #pragma unroll
    for (int j = 0; j < 4; ++j) acc[j] = 0.f;
    for (int i = s + g; i < t; i += 4) {
        int v = csr_e_v[i];
        if (act) {
            u16x4 y = *(const u16x4*)(Xp2b + (size_t)v * NC + c * 4);
            acc[0] += bf2f(y.x);
            acc[1] += bf2f(y.y);
            acc[2] += bf2f(y.z);
            acc[3] += bf2f(y.w);
        }
    }
    #pragma unroll
    for (int j = 0; j < 4; ++j) {
        acc[j] += __shfl_xor(acc[j], 16);
        acc[j] += __shfl_xor(acc[j], 32);
    }
    int deg = t - s;
    float inv = 1.f / (float)(deg > 1 ? deg : 1);
    float p = 0.f;
    if (act) {
        float4 ae = *(const float4*)(ae2 + c * 4);
        float y0 = acc[0] * inv, y1 = acc[1] * inv, y2 = acc[2] * inv, y3 = acc[3] * inv;
        p = y0 * ae.x + y1 * ae.y + y2 * ae.z + y3 * ae.w;
        if (g == 0) {
            u16x4 r = {f2bf(y0), f2bf(y1), f2bf(y2), f2bf(y3)};
            *(u16x4*)(Y2b + (size_t)wave * NC + c * 4) = r;
        }
    }
    #pragma unroll
    for (int off = 8; off >= 1; off >>= 1) p += __shfl_xor(p, off);
    if (lane == 0) se2[wave] = p;
}

__global__ void k_node_pass2(const u16* __restrict__ Y2b, const float* __restrict__ se2,
                             const float* __restrict__ sv2, const int* __restrict__ start_v,
                             const int* __restrict__ deg_va, const int* __restrict__ csr_v_e,
                             float* __restrict__ out, int N) {
    int wave = (blockIdx.x * blockDim.x + threadIdx.x) >> 6;
    int lane = threadIdx.x & 63;
    if (wave >= N) return;
    int s = start_v[wave], t = s + deg_va[wave];
    int g = lane >> 4, c = lane & 15;
    bool act = c < 10;
    float* orow = out + (size_t)wave * NC;
    if (t == s) {
        if (g == 0 && act) *(float4*)(orow + c * 4) = make_float4(0.f, 0.f, 0.f, 0.f);
        return;
    }
    float svv = sv2[wave];
    float den = 0.f;
    float acc[4];
    #pragma unroll
    for (int j = 0; j < 4; ++j) acc[j] = 0.f;
    for (int i = s + g; i < t; i += 4) {
        int e = csr_v_e[i];
        float x = se2[e] + svv;
        x = fmaxf(x, 0.2f * x);
        float ex = __expf(x);
        den += ex;
        if (act) {
            u16x4 y = *(const u16x4*)(Y2b + (size_t)e * NC + c * 4);
            acc[0] += ex * bf2f(y.x);
            acc[1] += ex * bf2f(y.y);
            acc[2] += ex * bf2f(y.z);
            acc[3] += ex * bf2f(y.w);
        }
    }
    den += __shfl_xor(den, 16);
    den += __shfl_xor(den, 32);
    #pragma unroll
    for (int j = 0; j < 4; ++j) {
        acc[j] += __shfl_xor(acc[j], 16);
        acc[j] += __shfl_xor(acc[j], 32);
    }
    if (g == 0 && act) {
        float inv = 1.f / den;
        float4 o;
        float* op = &o.x;
        #pragma unroll
        for (int j = 0; j < 4; ++j) {
            float v = acc[j] * inv;
            op[j] = v > 0.f ? v : __expf(v) - 1.f;
        }
        *(float4*)(orow + c * 4) = o;
    }
}

// ---------------- launcher ----------------
extern "C" void kernel_launch(void* const* d_in, const int* in_sizes, int n_in,
                              void* d_out, int out_size, void* d_ws, size_t ws_size,
                              hipStream_t stream) {
    const float* x0 = (const float*)d_in[0];
    const float* x1 = (const float*)d_in[1];
    const float* W1 = (const float*)d_in[2];
    const float* b1 = (const float*)d_in[3];
    const float* ae1 = (const float*)d_in[4];
    const float* av1 = (const float*)d_in[5];
    const float* W2 = (const float*)d_in[6];
    const float* b2 = (const float*)d_in[7];
    const float* ae2 = (const float*)d_in[8];
    const float* av2 = (const float*)d_in[9];
    const int* pe = (const int*)d_in[10];
    const int* pv = (const int*)d_in[11];

    const int N = in_sizes[0] / DIN;  // 100000
    const int P = in_sizes[10];       // 1600000
    const int E = E_CONST;            // 20000
    const int NBKT_V = (N + SUBD_V - 1) / SUBD_V;   // 196
    const int NBKT_E = (E + SUBD_E - 1) / SUBD_E;   // 157

    char* base = (char*)d_ws;
    auto alloc = [&](size_t bytes) -> void* {
        void* p = (void*)base;
        base += (bytes + 255) & ~(size_t)255;
        return p;
    };
    u16* Xbi = (u16*)alloc((size_t)N * 256 * 2);
    u16* hbuf = (u16*)alloc((size_t)N * DCAT * 2);
    u16* Xbar0 = (u16*)alloc((size_t)E * DIN * 2);
    u16* Xbar1 = (u16*)alloc((size_t)E * DIN * 2);
    u16* Ycat = (u16*)alloc((size_t)E * 512 * 2);
    u16* Xp2b = (u16*)alloc((size_t)N * NC * 2);
    u16* Y2b = (u16*)alloc((size_t)E * NC * 2);
    float* se8 = (float*)alloc((size_t)8 * E * 4);   // slice-major [8][E]
    float* se2 = (float*)alloc((size_t)E * 4);
    float* sv8 = (float*)alloc((size_t)8 * N * 4);   // slice-major [8][N]
    float* sv2 = (float*)alloc((size_t)N * 4);
    float* wav = (float*)alloc((size_t)NH * DIN * 4);
    float* bav = (float*)alloc((size_t)NH * 4);
    u16* WcatT = (u16*)alloc((size_t)256 * DIN * 2);
    u16* W2T = (u16*)alloc((size_t)48 * DCAT * 2);
    uint2* sorted_v = (uint2*)alloc((size_t)P * 8);
    uint2* sorted_e = (uint2*)alloc((size_t)P * 8);
    int* start_v = (int*)alloc((size_t)N * 4);
    int* deg_v = (int*)alloc((size_t)N * 4);
    int* start_e = (int*)alloc((size_t)E * 4);
    int* deg_e = (int*)alloc((size_t)E * 4);
    int* csr_v_e = (int*)alloc((size_t)P * 4);
    int* csr_e_v = (int*)alloc((size_t)P * 4);
    char* zstart = base;
    int* bstart_v = (int*)alloc((size_t)(NBKT_V + 1) * 4);
    int* bstart_e = (int*)alloc((size_t)(NBKT_E + 1) * 4);
    int* cur_v = (int*)alloc((size_t)256 * 4);
    int* cur_e = (int*)alloc((size_t)256 * 4);
    size_t zbytes = (size_t)(base - zstart);

    if ((size_t)(base - (char*)d_ws) > ws_size) return;

    hipMemsetAsync(zstart, 0, zbytes, stream);

    dim3 b256(256);
    int nA = (P + CHUNKA - 1) / CHUNKA;   // 391
    k_hist2<<<nA, b256, 0, stream>>>(pv, pe, bstart_v, bstart_e, P);
    k_scan_small<<<1, 1024, 0, stream>>>(bstart_v, NBKT_V);
    k_scan_small<<<1, 1024, 0, stream>>>(bstart_e, NBKT_E);
    k_scatter2way<<<nA, b256, 0, stream>>>(pv, pe, bstart_v, bstart_e, cur_v, cur_e,
                                           sorted_v, sorted_e, P);
    k_build_ord<SUBD_V, SH_V, NSUB_E, ECH><<<NBKT_V, b256, 0, stream>>>(sorted_v, bstart_v,
                                                                        start_v, deg_v,
                                                                        csr_v_e, N);
    k_build_ord<SUBD_E, SH_E, NSUB_V, VCH><<<NBKT_E, b256, 0, stream>>>(sorted_e, bstart_e,
                                                                        start_e, deg_e,
                                                                        csr_e_v, E);

    k_wav<<<NH, DIN, 0, stream>>>(W1, b1, av1, wav, bav);
    k_build_wcatT<<<(256 * DIN + 255) / 256, b256, 0, stream>>>(W1, WcatT);
    k_build_w2T<<<(48 * DCAT + 255) / 256, b256, 0, stream>>>(W2, W2T);

    int gN4 = (N + 3) / 4;
    int gE4 = (E + 3) / 4;
    dim3 gconv(gN4, 2);
    k_conv<<<gconv, b256, 0, stream>>>(x0, x1, wav, bav, Xbi, sv8, N);

    k_edge_mean1<<<gE4, b256, 0, stream>>>(Xbi, start_e, deg_e, csr_e_v, Xbar0, Xbar1, E);
    dim3 g1((E + 63) / 64, 2, 2);
    k_gemm_mfma<DIN, 8, 1><<<g1, b256, 0, stream>>>(Xbar0, Xbar1, E, WcatT, b1,
                                                    Ycat, Ycat + 256, 512, 256, ae1, se8);
    int gnp1 = ((N + 31) / 32) * 8;   // 25000 blocks; bid&7 = slice -> XCD
    k_node_pass1<<<gnp1, b256, 0, stream>>>(Ycat, se8, sv8, start_v, deg_v, csr_v_e,
                                            hbuf, N, E);

    dim3 g2((N + 63) / 64, 1, 1);
    k_gemm_mfma<DCAT, 3, 2><<<g2, b256, 0, stream>>>(hbuf, hbuf, N, W2T, b2, Xp2b, Xp2b,
                                                     NC, NC, av2, sv2);
    k_edge_mean2<<<gE4, b256, 0, stream>>>(Xp2b, start_e, deg_e, csr_e_v, Y2b, ae2, se2, E);
    k_node_pass2<<<gN4, b256, 0, stream>>>(Y2b, se2, sv2, start_v, deg_v, csr_v_e,
                                           (float*)d_out, N);
}

// Round 12
// 600.503 us; speedup vs baseline: 1.2026x; 1.0699x over previous
//
#include <hip/hip_runtime.h>
#include <cstdint>
#include <cstddef>

// N=100000, E=20000, P=1600000, din=128, dh=64, H=4, DCAT=512, C=40
static constexpr int DIN = 128;
static constexpr int DH = 64;
static constexpr int NH = 4;
static constexpr int DCAT = 512;
static constexpr int NC = 40;
static constexpr int E_CONST = 20000;
static constexpr int SH_V = 9, SUBD_V = 512;
static constexpr int SH_E = 7, SUBD_E = 128;
static constexpr int ECH = 11, NSUB_E = 10;
static constexpr int VCH = 12, NSUB_V = 25;
static constexpr int CHUNKA = 4096;

typedef unsigned short u16;
typedef __attribute__((ext_vector_type(4))) unsigned short u16x4;
typedef __attribute__((ext_vector_type(8))) unsigned short u16x8;
typedef __attribute__((ext_vector_type(8))) short bf16x8;
typedef __attribute__((ext_vector_type(4))) float f32x4;

static __device__ __forceinline__ float bf2f(u16 u) {
    union { unsigned int i; float f; } x;
    x.i = ((unsigned int)u) << 16;
    return x.f;
}
static __device__ __forceinline__ u16 f2bf(float f) {
    union { float f; unsigned int i; } x;
    x.f = f;
    unsigned int r = x.i + 0x7fffu + ((x.i >> 16) & 1u);
    return (u16)(r >> 16);
}

// ---------------- CSR build ----------------

__global__ void k_hist2(const int* __restrict__ pv, const int* __restrict__ pe,
                        int* __restrict__ btot_v, int* __restrict__ btot_e, int P) {
    __shared__ int cv[256], ce[256];
    int tid = threadIdx.x;
    cv[tid] = 0; ce[tid] = 0;
    __syncthreads();
    int p0 = blockIdx.x * CHUNKA;
    #pragma unroll
    for (int j = 0; j < CHUNKA / 256; ++j) {
        int p = p0 + tid + j * 256;
        if (p < P) {
            atomicAdd(&cv[pv[p] >> SH_V], 1);
            atomicAdd(&ce[pe[p] >> SH_E], 1);
        }
    }
    __syncthreads();
    if (cv[tid]) atomicAdd(&btot_v[tid], cv[tid]);
    if (ce[tid]) atomicAdd(&btot_e[tid], ce[tid]);
}

static __device__ void scan_body(int* a, int n) {
    __shared__ int wsum[16];
    __shared__ int carry_s;
    int tid = threadIdx.x;
    int lane = tid & 63;
    int w = tid >> 6;
    if (tid == 0) carry_s = 0;
    __syncthreads();
    for (int base = 0; base < n; base += 1024) {
        int i = base + tid;
        int v = (i < n) ? a[i] : 0;
        int x = v;
        #pragma unroll
        for (int off = 1; off < 64; off <<= 1) {
            int t = __shfl_up(x, off);
            if (lane >= off) x += t;
        }
        if (lane == 63) wsum[w] = x;
        __syncthreads();
        int woff = 0;
        for (int k = 0; k < w; ++k) woff += wsum[k];
        int carry = carry_s;
        if (i < n) a[i] = carry + woff + x - v;
        int tot = 0;
        for (int k = 0; k < 16; ++k) tot += wsum[k];
        __syncthreads();
        if (tid == 0) carry_s = carry + tot;
        __syncthreads();
    }
    if (tid == 0) a[n] = carry_s;
}

__global__ void k_scan_both(int* __restrict__ a, int na, int* __restrict__ b, int nb) {
    if (blockIdx.x == 0) scan_body(a, na);
    else scan_body(b, nb);
}

__global__ void k_scatter2way(const int* __restrict__ pv, const int* __restrict__ pe,
                              const int* __restrict__ bstart_v, const int* __restrict__ bstart_e,
                              int* __restrict__ cur_v, int* __restrict__ cur_e,
                              uint2* __restrict__ sorted_v, uint2* __restrict__ sorted_e, int P) {
    __shared__ int cv[256], ce[256], posv[256], pose[256];
    int tid = threadIdx.x;
    cv[tid] = 0; ce[tid] = 0;
    __syncthreads();
    int p0 = blockIdx.x * CHUNKA;
    int kv[CHUNKA / 256], ke[CHUNKA / 256];
    #pragma unroll
    for (int j = 0; j < CHUNKA / 256; ++j) {
        int p = p0 + tid + j * 256;
        if (p < P) {
            kv[j] = pv[p];
            ke[j] = pe[p];
            atomicAdd(&cv[kv[j] >> SH_V], 1);
            atomicAdd(&ce[ke[j] >> SH_E], 1);
        } else {
            kv[j] = -1;
            ke[j] = -1;
        }
    }
    __syncthreads();
    if (cv[tid]) posv[tid] = bstart_v[tid] + atomicAdd(&cur_v[tid], cv[tid]);
    if (ce[tid]) pose[tid] = bstart_e[tid] + atomicAdd(&cur_e[tid], ce[tid]);
    __syncthreads();
    #pragma unroll
    for (int j = 0; j < CHUNKA / 256; ++j) {
        if (kv[j] >= 0) {
            int iv = atomicAdd(&posv[kv[j] >> SH_V], 1);
            sorted_v[iv] = make_uint2((unsigned)kv[j], (unsigned)ke[j]);
            int ie = atomicAdd(&pose[ke[j] >> SH_E], 1);
            sorted_e[ie] = make_uint2((unsigned)ke[j], (unsigned)kv[j]);
        }
    }
}

template <int SUBD, int SH, int NSUB, int CSH>
__global__ __launch_bounds__(256) void k_build_ord(const uint2* __restrict__ sorted,
                                                   const int* __restrict__ bstart,
                                                   int* __restrict__ start_out,
                                                   int* __restrict__ deg_out,
                                                   int* __restrict__ csr_out, int D) {
    constexpr int NK2 = SUBD * NSUB;
    constexpr int STRIP = (NK2 + 255) / 256;
    __shared__ int cnt[NK2];
    __shared__ int wsum[4];
    int b = blockIdx.x;
    int tid = threadIdx.x;
    int base_key = b << SH;
    int s0 = bstart[b];
    int cntN = bstart[b + 1] - s0;
    for (int k = tid; k < NK2; k += 256) cnt[k] = 0;
    __syncthreads();
    for (int i = tid; i < cntN; i += 256) {
        uint2 pr = sorted[s0 + i];
        int k2 = ((int)pr.x - base_key) * NSUB + ((int)pr.y >> CSH);
        atomicAdd(&cnt[k2], 1);
    }
    __syncthreads();
    int local[STRIP];
    int sum = 0;
    int t0 = tid * STRIP;
    #pragma unroll
    for (int j = 0; j < STRIP; ++j) {
        int idx = t0 + j;
        local[j] = (idx < NK2) ? cnt[idx] : 0;
        sum += local[j];
    }
    int lane = tid & 63, w = tid >> 6;
    int x = sum;
    #pragma unroll
    for (int off = 1; off < 64; off <<= 1) {
        int t = __shfl_up(x, off);
        if (lane >= off) x += t;
    }
    if (lane == 63) wsum[w] = x;
    __syncthreads();
    int woff = 0;
    for (int k = 0; k < w; ++k) woff += wsum[k];
    int run = woff + x - sum;
    __syncthreads();
    #pragma unroll
    for (int j = 0; j < STRIP; ++j) {
        int idx = t0 + j;
        if (idx < NK2) {
            int tmp = local[j];
            cnt[idx] = run;
            run += tmp;
        }
    }
    __syncthreads();
    for (int loc = tid; loc < SUBD; loc += 256) {
        int key = base_key + loc;
        if (key < D) {
            int st = cnt[loc * NSUB];
            int en = (loc == SUBD - 1) ? cntN : cnt[(loc + 1) * NSUB];
            start_out[key] = s0 + st;
            deg_out[key] = en - st;
        }
    }
    __syncthreads();
    for (int i = tid; i < cntN; i += 256) {
        uint2 pr = sorted[s0 + i];
        int k2 = ((int)pr.x - base_key) * NSUB + ((int)pr.y >> CSH);
        int idx = atomicAdd(&cnt[k2], 1);
        csr_out[s0 + idx] = (int)pr.y;
    }
}

// ---------------- fused weight prep ----------------
__global__ void k_prep(const float* __restrict__ W1, const float* __restrict__ b1,
                       const float* __restrict__ av1, const float* __restrict__ W2,
                       float* __restrict__ wav, float* __restrict__ bav,
                       u16* __restrict__ WcatT, u16* __restrict__ W2T) {
    int bid = blockIdx.x;
    int tid = threadIdx.x;
    if (bid < 4) {
        int h = bid;
        if (tid < DIN) {
            float s = 0.f;
            for (int j = 0; j < DH; ++j)
                s += W1[(size_t)(h * DIN + tid) * DH + j] * av1[h * DH + j];
            wav[h * DIN + tid] = s;
        }
        if (tid == 0) {
            float t = 0.f;
            for (int j = 0; j < DH; ++j) t += b1[h * DH + j] * av1[h * DH + j];
            bav[h] = t;
        }
    } else if (bid < 4 + 128) {
        int idx = (bid - 4) * 256 + tid;
        int c = idx >> 7, k = idx & 127;
        int h = c >> 6, j = c & 63;
        WcatT[c * DIN + k] = f2bf(W1[((size_t)h * DIN + k) * DH + j]);
    } else {
        int idx = (bid - 132) * 256 + tid;
        int c = idx >> 9, k = idx & 511;
        float v = (c < NC) ? W2[(size_t)k * NC + c] : 0.f;
        W2T[c * DCAT + k] = f2bf(v);
    }
}

// ---------------- conversion + node attention term ----------------
__global__ void k_conv(const float* __restrict__ X0, const float* __restrict__ X1,
                       const float* __restrict__ wav, const float* __restrict__ bav,
                       u16* __restrict__ Xbi, float* __restrict__ sv8, int N) {
    int wave = (blockIdx.x * blockDim.x + threadIdx.x) >> 6;
    int lane = threadIdx.x & 63;
    if (wave >= N) return;
    int xz = blockIdx.y;
    const float* X = xz ? X1 : X0;
    float2 a = *(const float2*)(X + (size_t)wave * DIN + lane * 2);
    unsigned int packed = (unsigned int)f2bf(a.x) | ((unsigned int)f2bf(a.y) << 16);
    *(unsigned int*)(Xbi + (size_t)wave * 256 + xz * 128 + lane * 2) = packed;
    float s[NH];
    #pragma unroll
    for (int h = 0; h < NH; ++h) {
        float2 wv = *(const float2*)(wav + h * DIN + lane * 2);
        float t = a.x * wv.x + a.y * wv.y;
        #pragma unroll
        for (int off = 32; off >= 1; off >>= 1) t += __shfl_xor(t, off);
        s[h] = t;
    }
    if (lane == 0) {
        #pragma unroll
        for (int h = 0; h < NH; ++h) sv8[(size_t)(xz * 4 + h) * N + wave] = s[h] + bav[h];
    }
}

// ---------------- edge mean (layer 1) ----------------
__global__ void k_edge_mean1(const u16* __restrict__ Xbi, const int* __restrict__ start_e,
                             const int* __restrict__ deg_e, const int* __restrict__ csr_e_v,
                             u16* __restrict__ Xbar0, u16* __restrict__ Xbar1, int E) {
    int wave = (blockIdx.x * blockDim.x + threadIdx.x) >> 6;
    int lane = threadIdx.x & 63;
    if (wave >= E) return;
    int s = start_e[wave], t = s + deg_e[wave];
    int q = lane >> 4, c = lane & 15;
    float a0[8], a1[8];
    #pragma unroll
    for (int j = 0; j < 8; ++j) { a0[j] = 0.f; a1[j] = 0.f; }
    int i = s + q;
    u16x8 y0A = {0}, y1A = {0}, y0B = {0}, y1B = {0}, y0C = {0}, y1C = {0};
#define EM1_LOAD(Y0, Y1, IDX) { int v_ = csr_e_v[IDX]; \
        const u16* yp_ = Xbi + (size_t)v_ * 256 + c * 8; \
        Y0 = *(const u16x8*)yp_; Y1 = *(const u16x8*)(yp_ + 128); }
#define EM1_CONSUME(Y0, Y1) { \
        _Pragma("unroll") \
        for (int j = 0; j < 8; ++j) { a0[j] += bf2f(Y0[j]); a1[j] += bf2f(Y1[j]); } }
    if (i < t) EM1_LOAD(y0A, y1A, i);
    if (i + 4 < t) EM1_LOAD(y0B, y1B, i + 4);
    if (i + 8 < t) EM1_LOAD(y0C, y1C, i + 8);
    for (; i + 8 < t; i += 12) {
        EM1_CONSUME(y0A, y1A);
        if (i + 12 < t) EM1_LOAD(y0A, y1A, i + 12);
        EM1_CONSUME(y0B, y1B);
        if (i + 16 < t) EM1_LOAD(y0B, y1B, i + 16);
        EM1_CONSUME(y0C, y1C);
        if (i + 20 < t) EM1_LOAD(y0C, y1C, i + 20);
    }
    if (i < t) EM1_CONSUME(y0A, y1A);
    if (i + 4 < t) EM1_CONSUME(y0B, y1B);
#undef EM1_LOAD
#undef EM1_CONSUME
    #pragma unroll
    for (int j = 0; j < 8; ++j) {
        a0[j] += __shfl_xor(a0[j], 16);
        a0[j] += __shfl_xor(a0[j], 32);
        a1[j] += __shfl_xor(a1[j], 16);
        a1[j] += __shfl_xor(a1[j], 32);
    }
    int deg = t - s;
    float inv = 1.f / (float)(deg > 1 ? deg : 1);
    if (q == 0) {
        u16x8 r0, r1;
        #pragma unroll
        for (int j = 0; j < 8; ++j) { r0[j] = f2bf(a0[j] * inv); r1[j] = f2bf(a1[j] * inv); }
        *(u16x8*)(Xbar0 + (size_t)wave * DIN + c * 8) = r0;
        *(u16x8*)(Xbar1 + (size_t)wave * DIN + c * 8) = r1;
    }
}

// ---------------- MFMA GEMM with fused row-dot epilogue ----------------
template <int KDIM, int NTILES, int DOTMODE>
__global__ __launch_bounds__(256) void k_gemm_mfma(const u16* __restrict__ A0,
                                                   const u16* __restrict__ A1, int M,
                                                   const u16* __restrict__ Bt,
                                                   const float* __restrict__ bias,
                                                   u16* __restrict__ out0, u16* __restrict__ out1,
                                                   int ldo, int ncols,
                                                   const float* __restrict__ dvec,
                                                   float* __restrict__ dout) {
    constexpr int LDB = KDIM + 8;
    __shared__ u16 Bs[NTILES * 16 * LDB];
    const u16* A = blockIdx.z ? A1 : A0;
    u16* out = blockIdx.z ? out1 : out0;
    int tid = threadIdx.x;
    int colbase = blockIdx.y * NTILES * 16;
    const u16* Btblk = Bt + (size_t)colbase * KDIM;
    for (int idx = tid * 4; idx < NTILES * 16 * KDIM; idx += 256 * 4) {
        int c = idx / KDIM, k = idx % KDIM;
        *(u16x4*)&Bs[c * LDB + k] = *(const u16x4*)(Btblk + c * KDIM + k);
    }
    __syncthreads();
    int w = tid >> 6, lane = tid & 63;
    int r0 = blockIdx.x * 64 + w * 16;
    int arow = r0 + (lane & 15);
    bool avalid = arow < M;
    const u16* ap = A + (size_t)arow * KDIM + (lane >> 4) * 8;
    f32x4 acc[NTILES];
    #pragma unroll
    for (int nt = 0; nt < NTILES; ++nt) acc[nt] = (f32x4){0.f, 0.f, 0.f, 0.f};
    #pragma unroll
    for (int k0 = 0; k0 < KDIM; k0 += 32) {
        bf16x8 a = (bf16x8)(short)0;
        if (avalid) a = *(const bf16x8*)(ap + k0);
        #pragma unroll
        for (int nt = 0; nt < NTILES; ++nt) {
            bf16x8 b = *(const bf16x8*)&Bs[(nt * 16 + (lane & 15)) * LDB + k0 + (lane >> 4) * 8];
            acc[nt] = __builtin_amdgcn_mfma_f32_16x16x32_bf16(a, b, acc[nt], 0, 0, 0);
        }
    }
    #pragma unroll
    for (int j = 0; j < 4; ++j) {
        int row = r0 + (lane >> 4) * 4 + j;
        float pA = 0.f, pB = 0.f;
        #pragma unroll
        for (int nt = 0; nt < NTILES; ++nt) {
            int col = colbase + nt * 16 + (lane & 15);
            bool cok = col < ncols;
            float val = cok ? acc[nt][j] + bias[col] : 0.f;
            if (DOTMODE == 1) {
                float dv = dvec[col];
                if (nt < NTILES / 2) pA += val * dv; else pB += val * dv;
            } else if (DOTMODE == 2) {
                pA += cok ? val * dvec[col] : 0.f;
            }
            if (row < M && cok) out[(size_t)row * ldo + col] = f2bf(val);
        }
        if (DOTMODE) {
            pA += __shfl_xor(pA, 1);
            pA += __shfl_xor(pA, 2);
            pA += __shfl_xor(pA, 4);
            pA += __shfl_xor(pA, 8);
            if (DOTMODE == 1) {
                pB += __shfl_xor(pB, 1);
                pB += __shfl_xor(pB, 2);
                pB += __shfl_xor(pB, 4);
                pB += __shfl_xor(pB, 8);
            }
            if ((lane & 15) == 0 && row < M) {
                if (DOTMODE == 1) {
                    int hbase = blockIdx.y * 2;
                    int z = blockIdx.z;
                    dout[(size_t)(z * 4 + hbase) * M + row] = pA;
                    dout[(size_t)(z * 4 + hbase + 1) * M + row] = pB;
                } else {
                    dout[row] = pA;
                }
            }
        }
    }
}

// ---------------- fused node pass (layer 1): XCD-sliced, group-per-node, 2-slot pipeline ----------------
__global__ void k_node_pass1(const u16* __restrict__ Ycat, const float* __restrict__ se8,
                             const float* __restrict__ sv8, const int* __restrict__ start_v,
                             const int* __restrict__ deg_v, const int* __restrict__ csr_v_e,
                             u16* __restrict__ hbuf, int N, int E) {
    int bid = blockIdx.x;
    int s = bid & 7;
    int warp = threadIdx.x >> 6;
    int lane = threadIdx.x & 63;
    int g = lane >> 3, c = lane & 7;
    int node = (bid >> 3) * 32 + warp * 8 + g;
    if (node >= N) return;
    int p0 = start_v[node];
    int p1 = p0 + deg_v[node];
    float sv = sv8[(size_t)s * N + node];
    const float* seS = se8 + (size_t)s * E;
    const u16* ybase = Ycat + s * 64 + c * 8;
    float den = 0.f;
    float acc[8];
    #pragma unroll
    for (int j = 0; j < 8; ++j) acc[j] = 0.f;
    float sA = 0.f, sB = 0.f;
    u16x8 yA = {0}, yB = {0};
#define NP1_LOAD(S, Y, IDX) { int e_ = csr_v_e[IDX]; S = seS[e_]; \
        Y = *(const u16x8*)(ybase + (size_t)e_ * 512); }
#define NP1_CONSUME(S, Y) { \
        float x_ = S + sv; x_ = fmaxf(x_, 0.2f * x_); float ex_ = __expf(x_); \
        den += ex_; \
        _Pragma("unroll") \
        for (int j = 0; j < 8; ++j) acc[j] += ex_ * bf2f(Y[j]); }
    int i = p0;
    if (i < p1) NP1_LOAD(sA, yA, i);
    if (i + 1 < p1) NP1_LOAD(sB, yB, i + 1);
    for (; i + 1 < p1; i += 2) {
        NP1_CONSUME(sA, yA);
        if (i + 2 < p1) NP1_LOAD(sA, yA, i + 2);
        NP1_CONSUME(sB, yB);
        if (i + 3 < p1) NP1_LOAD(sB, yB, i + 3);
    }
    if (i < p1) NP1_CONSUME(sA, yA);
#undef NP1_LOAD
#undef NP1_CONSUME
    float inv = (p1 > p0) ? 1.f / den : 0.f;
    u16x8 r;
    #pragma unroll
    for (int j = 0; j < 8; ++j) {
        float o = acc[j] * inv;
        o = o > 0.f ? o : __expf(o) - 1.f;
        r[j] = f2bf(o);
    }
    *(u16x8*)(hbuf + (size_t)node * DCAT + s * 64 + c * 8) = r;
}

// ---------------- layer 2: group-per-segment (8 groups x 8 lanes) ----------------

__global__ void k_edge_mean2(const u16* __restrict__ Xp2b, const int* __restrict__ start_e,
                             const int* __restrict__ deg_ea, const int* __restrict__ csr_e_v,
                             u16* __restrict__ Y2b, const float* __restrict__ ae2,
                             float* __restrict__ se2, int E) {
    int warp = threadIdx.x >> 6;
    int lane = threadIdx.x & 63;
    int g = lane >> 3, c = lane & 7;
    int edge = blockIdx.x * 32 + warp * 8 + g;
    if (edge >= E) return;
    int p0 = start_e[edge], p1 = p0 + deg_ea[edge];
    bool act = c < 5;
    const u16* xbase = Xp2b + c * 8;
    float acc[8];
    #pragma unroll
    for (int j = 0; j < 8; ++j) acc[j] = 0.f;
    if (act) {
        for (int i = p0; i < p1; ++i) {
            int v = csr_e_v[i];
            u16x8 y = *(const u16x8*)(xbase + (size_t)v * NC);
            #pragma unroll
            for (int j = 0; j < 8; ++j) acc[j] += bf2f(y[j]);
        }
    }
    int deg = p1 - p0;
    float inv = 1.f / (float)(deg > 1 ? deg : 1);
    float p = 0.f;
    if (act) {
        u16x8 r;
        #pragma unroll
        for (int j = 0; j < 8; ++j) {
            float y = acc[j] * inv;
            p += y * ae2[c * 8 + j];
            r[j] = f2bf(y);
        }
        *(u16x8*)(Y2b + (size_t)edge * NC + c * 8) = r;
    }
    p += __shfl_xor(p, 1);
    p += __shfl_xor(p, 2);
    p += __shfl_xor(p, 4);
    if (c == 0) se2[edge] = p;
}

__global__ void k_node_pass2(const u16* __restrict__ Y2b, const float* __restrict__ se2,
                             const float* __restrict__ sv2, const int* __restrict__ start_v,
                             const int* __restrict__ deg_va, const int* __restrict__ csr_v_e,
                             float* __restrict__ out, int N) {
    int warp = threadIdx.x >> 6;
    int lane = threadIdx.x & 63;
    int g = lane >> 3, c = lane & 7;
    int node = blockIdx.x * 32 + warp * 8 + g;
    if (node >= N) return;
    int p0 = start_v[node], p1 = p0 + deg_va[node];
    bool act = c < 5;
    float* orow = out + (size_t)node * NC;
    if (p1 == p0) {
        if (act) {
            *(float4*)(orow + c * 8) = make_float4(0.f, 0.f, 0.f, 0.f);
            *(float4*)(orow + c * 8 + 4) = make_float4(0.f, 0.f, 0.f, 0.f);
        }
        return;
    }
    float svv = sv2[node];
    const u16* ybase = Y2b + c * 8;
    float den = 0.f;
    float acc[8];
    #pragma unroll
    for (int j = 0; j < 8; ++j) acc[j] = 0.f;
    for (int i = p0; i < p1; ++i) {
        int e = csr_v_e[i];
        float x = se2[e] + svv;
        x = fmaxf(x, 0.2f * x);
        float ex = __expf(x);
        den += ex;
        if (act) {
            u16x8 y = *(const u16x8*)(ybase + (size_t)e * NC);
            #pragma unroll
            for (int j = 0; j < 8; ++j) acc[j] += ex * bf2f(y[j]);
        }
    }
    if (act) {
        float inv = 1.f / den;
        float o[8];
        #pragma unroll
        for (int j = 0; j < 8; ++j) {
            float v = acc[j] * inv;
            o[j] = v > 0.f ? v : __expf(v) - 1.f;
        }
        *(float4*)(orow + c * 8) = make_float4(o[0], o[1], o[2], o[3]);
        *(float4*)(orow + c * 8 + 4) = make_float4(o[4], o[5], o[6], o[7]);
    }
}

// ---------------- launcher ----------------
extern "C" void kernel_launch(void* const* d_in, const int* in_sizes, int n_in,
                              void* d_out, int out_size, void* d_ws, size_t ws_size,
                              hipStream_t stream) {
    const float* x0 = (const float*)d_in[0];
    const float* x1 = (const float*)d_in[1];
    const float* W1 = (const float*)d_in[2];
    const float* b1 = (const float*)d_in[3];
    const float* ae1 = (const float*)d_in[4];
    const float* av1 = (const float*)d_in[5];
    const float* W2 = (const float*)d_in[6];
    const float* b2 = (const float*)d_in[7];
    const float* ae2 = (const float*)d_in[8];
    const float* av2 = (const float*)d_in[9];
    const int* pe = (const int*)d_in[10];
    const int* pv = (const int*)d_in[11];

    const int N = in_sizes[0] / DIN;  // 100000
    const int P = in_sizes[10];       // 1600000
    const int E = E_CONST;            // 20000
    const int NBKT_V = (N + SUBD_V - 1) / SUBD_V;   // 196
    const int NBKT_E = (E + SUBD_E - 1) / SUBD_E;   // 157

    char* base = (char*)d_ws;
    auto alloc = [&](size_t bytes) -> void* {
        void* p = (void*)base;
        base += (bytes + 255) & ~(size_t)255;
        return p;
    };
    u16* Xbi = (u16*)alloc((size_t)N * 256 * 2);
    u16* hbuf = (u16*)alloc((size_t)N * DCAT * 2);
    u16* Xbar0 = (u16*)alloc((size_t)E * DIN * 2);
    u16* Xbar1 = (u16*)alloc((size_t)E * DIN * 2);
    u16* Ycat = (u16*)alloc((size_t)E * 512 * 2);
    u16* Xp2b = (u16*)alloc((size_t)N * NC * 2);
    u16* Y2b = (u16*)alloc((size_t)E * NC * 2);
    float* se8 = (float*)alloc((size_t)8 * E * 4);
    float* se2 = (float*)alloc((size_t)E * 4);
    float* sv8 = (float*)alloc((size_t)8 * N * 4);
    float* sv2 = (float*)alloc((size_t)N * 4);
    float* wav = (float*)alloc((size_t)NH * DIN * 4);
    float* bav = (float*)alloc((size_t)NH * 4);
    u16* WcatT = (u16*)alloc((size_t)256 * DIN * 2);
    u16* W2T = (u16*)alloc((size_t)48 * DCAT * 2);
    uint2* sorted_v = (uint2*)alloc((size_t)P * 8);
    uint2* sorted_e = (uint2*)alloc((size_t)P * 8);
    int* start_v = (int*)alloc((size_t)N * 4);
    int* deg_v = (int*)alloc((size_t)N * 4);
    int* start_e = (int*)alloc((size_t)E * 4);
    int* deg_e = (int*)alloc((size_t)E * 4);
    int* csr_v_e = (int*)alloc((size_t)P * 4);
    int* csr_e_v = (int*)alloc((size_t)P * 4);
    char* zstart = base;
    int* bstart_v = (int*)alloc((size_t)(NBKT_V + 1) * 4);
    int* bstart_e = (int*)alloc((size_t)(NBKT_E + 1) * 4);
    int* cur_v = (int*)alloc((size_t)256 * 4);
    int* cur_e = (int*)alloc((size_t)256 * 4);
    size_t zbytes = (size_t)(base - zstart);

    if ((size_t)(base - (char*)d_ws) > ws_size) return;

    hipMemsetAsync(zstart, 0, zbytes, stream);

    dim3 b256(256);
    int nA = (P + CHUNKA - 1) / CHUNKA;   // 391
    k_hist2<<<nA, b256, 0, stream>>>(pv, pe, bstart_v, bstart_e, P);
    k_scan_both<<<2, 1024, 0, stream>>>(bstart_v, NBKT_V, bstart_e, NBKT_E);
    k_scatter2way<<<nA, b256, 0, stream>>>(pv, pe, bstart_v, bstart_e, cur_v, cur_e,
                                           sorted_v, sorted_e, P);
    k_build_ord<SUBD_V, SH_V, NSUB_E, ECH><<<NBKT_V, b256, 0, stream>>>(sorted_v, bstart_v,
                                                                        start_v, deg_v,
                                                                        csr_v_e, N);
    k_build_ord<SUBD_E, SH_E, NSUB_V, VCH><<<NBKT_E, b256, 0, stream>>>(sorted_e, bstart_e,
                                                                        start_e, deg_e,
                                                                        csr_e_v, E);

    k_prep<<<228, b256, 0, stream>>>(W1, b1, av1, W2, wav, bav, WcatT, W2T);

    int gN4 = (N + 3) / 4;
    int gE4 = (E + 3) / 4;
    dim3 gconv(gN4, 2);
    k_conv<<<gconv, b256, 0, stream>>>(x0, x1, wav, bav, Xbi, sv8, N);

    k_edge_mean1<<<gE4, b256, 0, stream>>>(Xbi, start_e, deg_e, csr_e_v, Xbar0, Xbar1, E);
    dim3 g1((E + 63) / 64, 2, 2);
    k_gemm_mfma<DIN, 8, 1><<<g1, b256, 0, stream>>>(Xbar0, Xbar1, E, WcatT, b1,
                                                    Ycat, Ycat + 256, 512, 256, ae1, se8);
    int gnp1 = ((N + 31) / 32) * 8;
    k_node_pass1<<<gnp1, b256, 0, stream>>>(Ycat, se8, sv8, start_v, deg_v, csr_v_e,
                                            hbuf, N, E);

    dim3 g2((N + 63) / 64, 1, 1);
    k_gemm_mfma<DCAT, 3, 2><<<g2, b256, 0, stream>>>(hbuf, hbuf, N, W2T, b2, Xp2b, Xp2b,
                                                     NC, NC, av2, sv2);
    int gseg = (E + 31) / 32;
    k_edge_mean2<<<gseg, b256, 0, stream>>>(Xp2b, start_e, deg_e, csr_e_v, Y2b, ae2, se2, E);
    int gnp2 = (N + 31) / 32;
    k_node_pass2<<<gnp2, b256, 0, stream>>>(Y2b, se2, sv2, start_v, deg_v, csr_v_e,
                                            (float*)d_out, N);
}